// Round 5
// baseline (619.647 us; speedup 1.0000x reference)
//
#include <hip/hip_runtime.h>

// HashRoutedSSMLayer: B=8,S=2048,D=1024,N=256,H=512,E=8 — fp32 in/out.
// Round 9: A-panel-RESIDENT grouped GEMM. Each block stages its A tile
// (BM x KD, <=128KB) into LDS ONCE, then loops over N-column chunks (128 wide)
// streaming only B (8KB/step, 3-buf, counted vmcnt, 1 barrier/step).
// Per-block pipeline: 64-192 steps (vs 16) -> prologue/drain amortized;
// per-step global traffic 4x lower; A fetched from HBM exactly once.
// MODE 0: BM=64 (K=1024), 4 waves, new 64-row tile table.
// MODE 1/2: BM=128 (K=512/256), 8 waves, 128-row tiles x 2 col-halves.

#define TOKS 16384
#define RPAD 16512      // TOKS + 128 pad rows for tile overread
#define DD   1024
#define NN   256
#define HH   512
#define MAXTILES  136   // sum ceil(ce/128) <= 128+8
#define MAXT64    272   // sum ceil(ce/64)  <= 256+8
#define MAXCHUNKS 1088  // sum ceil(n_g/16) <= 1024+64
#define CHUNK 16

typedef short short8 __attribute__((ext_vector_type(8)));
typedef float floatx4 __attribute__((ext_vector_type(4)));
typedef _Float16 half_t;

#define AS_GLOBAL __attribute__((address_space(1)))
#define AS_LDS    __attribute__((address_space(3)))

__device__ __forceinline__ void gl_lds16(const void* g, void* l) {
    __builtin_amdgcn_global_load_lds((const AS_GLOBAL void*)g, (AS_LDS void*)l, 16, 0, 0);
}

__device__ __forceinline__ unsigned short f2bf(float f) {
    union { float f; unsigned u; } c; c.f = f;
    unsigned r = c.u + 0x7FFF + ((c.u >> 16) & 1);
    return (unsigned short)(r >> 16);
}
__device__ __forceinline__ int route_of(int token) {
    unsigned x = (unsigned)token;
    x ^= x >> 16; x *= 2246822507u; x ^= x >> 13; x *= 3266489909u; x ^= x >> 16;
    return (int)(x & 7u);
}
__device__ __forceinline__ float sigm(float v) { return 1.0f / (1.0f + __expf(-v)); }
__device__ __forceinline__ float ftanh(float v) {
    float e = __expf(2.0f * v);          // inf-safe: v>>0 -> 1, v<<0 -> -1
    return 1.0f - 2.0f / (e + 1.0f);
}

// ---------------- K1: per-row route histogram ----------------
__global__ void k_route(const int* __restrict__ tok, int* __restrict__ cnt) {
    int b = blockIdx.x, tid = threadIdx.x;
    __shared__ int lc[256 * 8];
    #pragma unroll
    for (int e = 0; e < 8; e++) lc[tid * 8 + e] = 0;
    #pragma unroll
    for (int i = 0; i < 8; i++) {
        int e = route_of(tok[b * 2048 + tid * 8 + i]);
        lc[tid * 8 + e]++;
    }
    __syncthreads();
    if (tid < 8) {
        int s = 0;
        for (int t = 0; t < 256; t++) s += lc[t * 8 + tid];
        cnt[b * 8 + tid] = s;
    }
}

// ---------------- K2: offsets + tile tables (128 & 64) + chunk table ----------------
__global__ void k_offsets(const int* __restrict__ cnt, int* __restrict__ grpoff,
                          int* __restrict__ tileE, int* __restrict__ tileS,
                          int* __restrict__ tileR,
                          int* __restrict__ tE64, int* __restrict__ tS64,
                          int* __restrict__ tR64,
                          int* __restrict__ cGrp, int* __restrict__ cStart,
                          int* __restrict__ cLen, int* __restrict__ gBase,
                          int* __restrict__ meta) {
    __shared__ int sc[64], ce[8], eoff[9], etile[9], et64[9], gb[65], go[64];
    int tid = threadIdx.x;
    if (tid < 64) sc[tid] = cnt[tid];
    __syncthreads();
    if (tid < 8) { int s = 0; for (int b = 0; b < 8; b++) s += sc[b * 8 + tid]; ce[tid] = s; }
    __syncthreads();
    if (tid == 0) {
        eoff[0] = 0; etile[0] = 0; et64[0] = 0;
        for (int e = 0; e < 8; e++) {
            eoff[e + 1] = eoff[e] + ce[e];
            etile[e + 1] = etile[e] + (ce[e] + 127) / 128;
            et64[e + 1] = et64[e] + (ce[e] + 63) / 64;
        }
        meta[0] = etile[8];
        meta[2] = et64[8];
        gb[0] = 0;
        for (int g = 0; g < 64; g++) gb[g + 1] = gb[g] + (sc[g] + CHUNK - 1) / CHUNK;
        meta[1] = gb[64];
    }
    __syncthreads();
    if (tid < 64) {
        int b = tid >> 3, e = tid & 7;
        int run = eoff[e];
        for (int b2 = 0; b2 < b; b2++) run += sc[b2 * 8 + e];
        go[tid] = run;
        grpoff[tid] = run;
    }
    __syncthreads();
    if (tid < 8) {   // 128-row tiles for expert tid
        int e = tid, st = eoff[e], c = ce[e], t0 = etile[e];
        for (int i = 0, k = 0; i < c; i += 128, k++) {
            tileE[t0 + k] = e; tileS[t0 + k] = st + i;
            tileR[t0 + k] = (c - i < 128) ? (c - i) : 128;
        }
    }
    if (tid >= 8 && tid < 16) {   // 64-row tiles for expert tid-8
        int e = tid - 8, st = eoff[e], c = ce[e], t0 = et64[e];
        for (int i = 0, k = 0; i < c; i += 64, k++) {
            tE64[t0 + k] = e; tS64[t0 + k] = st + i;
            tR64[t0 + k] = (c - i < 64) ? (c - i) : 64;
        }
    }
    if (tid < 64) {  // chunks for group tid
        int g = tid, n = sc[g], base = gb[g], s0 = go[g];
        gBase[g] = base;
        for (int i = 0, c = 0; i < n; i += CHUNK, c++) {
            cGrp[base + c] = g;
            cStart[base + c] = s0 + i;
            cLen[base + c] = (n - i < CHUNK) ? (n - i) : CHUNK;
        }
    }
}

// ---------------- K3: stable counting-sort scatter ----------------
__global__ void k_scatter(const int* __restrict__ tok, const int* __restrict__ grpoff,
                          int* __restrict__ perm) {
    int b = blockIdx.x, tid = threadIdx.x;
    __shared__ int lh[8 * 256];
    int r[8];
    int myc[8] = {0,0,0,0,0,0,0,0};
    #pragma unroll
    for (int i = 0; i < 8; i++) {
        int e = route_of(tok[b * 2048 + tid * 8 + i]);
        r[i] = e; myc[e]++;
    }
    #pragma unroll
    for (int e = 0; e < 8; e++) lh[e * 256 + tid] = myc[e];
    __syncthreads();
    for (int e = 0; e < 8; e++) {
        for (int off = 1; off < 256; off <<= 1) {
            int add = (tid >= off) ? lh[e * 256 + tid - off] : 0;
            __syncthreads();
            lh[e * 256 + tid] += add;
            __syncthreads();
        }
    }
    int basep[8];
    #pragma unroll
    for (int e = 0; e < 8; e++) basep[e] = grpoff[b * 8 + e] + lh[e * 256 + tid] - myc[e];
    #pragma unroll
    for (int i = 0; i < 8; i++) {
        int e = r[i];
        perm[basep[e]++] = b * 2048 + tid * 8 + i;
    }
}

// ---------------- K4: weights fp32 -> bf16 (W12 = [Win|Wsin] concat) ----------------
__global__ void k_cvtw(const float* __restrict__ Win, const float* __restrict__ Wsin,
                       const float* __restrict__ Wsout, const float* __restrict__ Wout,
                       unsigned short* __restrict__ W12, unsigned short* __restrict__ Wso,
                       unsigned short* __restrict__ Wo) {
    const int C12 = 8 * 768 * 1024 / 4, CSO = 8 * 1024 * 512 / 4, CWO = 8 * 1024 * 256 / 4;
    int c = blockIdx.x * 256 + threadIdx.x;
    float4 v; unsigned short* dst;
    if (c < C12) {
        int d = c * 4;
        int e = d / (768 * 1024);
        int rem = d - e * (768 * 1024);
        int r = rem >> 10, k = rem & 1023;
        const float* src = (r < 256) ? (Win + (((size_t)e * 256 + r) << 10) + k)
                                     : (Wsin + (((size_t)e * 512 + (r - 256)) << 10) + k);
        v = *(const float4*)src;
        dst = W12 + d;
    } else if (c < C12 + CSO) {
        int d = (c - C12) * 4;
        v = *(const float4*)(Wsout + d);
        dst = Wso + d;
    } else if (c < C12 + CSO + CWO) {
        int d = (c - C12 - CSO) * 4;
        v = *(const float4*)(Wout + d);
        dst = Wo + d;
    } else return;
    ushort4 o;
    o.x = f2bf(v.x); o.y = f2bf(v.y); o.z = f2bf(v.z); o.w = f2bf(v.w);
    *(ushort4*)dst = o;
}

// ---------------- K5: gather x into sorted bf16 rows + zero pads ----------------
__global__ void k_gather(const float* __restrict__ x, const int* __restrict__ perm,
                         unsigned short* __restrict__ Xs, unsigned short* __restrict__ SHb,
                         unsigned short* __restrict__ Yb) {
    int r = blockIdx.x, t = threadIdx.x;
    if (r < TOKS) {
        int tok = perm[r];
        float4 v = *(const float4*)(x + (size_t)tok * 1024 + t * 4);
        ushort4 o;
        o.x = f2bf(v.x); o.y = f2bf(v.y); o.z = f2bf(v.z); o.w = f2bf(v.w);
        *(ushort4*)(Xs + (size_t)r * 1024 + t * 4) = o;
    } else {
        ushort4 z = {0, 0, 0, 0};
        *(ushort4*)(Xs + (size_t)r * 1024 + t * 4) = z;
        if (t < 128) *(ushort4*)(SHb + (size_t)r * 512 + t * 4) = z;
        if (t < 64)  *(ushort4*)(Yb + (size_t)r * 256 + t * 4) = z;
    }
}

// ---------------- A-resident MFMA grouped GEMM ----------------
// A (BM x KD) resident in LDS (slices of 32-K, XOR-swizzled chunks as before).
// Loop over COLS_PB column chunks of 128; B streamed per 32-K step via 3-buf
// counted-vmcnt pipeline (round-8 pattern, proven race-free).
// Wave partition: WM = BM/64 (1 or 2), WN = waves/WM = 4, NJ = 2 (32 cols/wave).
template<int MODE, int KD, int BM, int THR, int COLS_PB, int MIDX, int MINW>
__global__ __launch_bounds__(THR, MINW)
void k_mfma(const unsigned short* __restrict__ A, const unsigned short* __restrict__ Bw,
            const int* __restrict__ perm, const float* __restrict__ dparam,
            half_t* __restrict__ Ub, unsigned short* __restrict__ SHb,
            half_t* __restrict__ Aa, half_t* __restrict__ Wg,
            half_t* __restrict__ Cc, half_t* __restrict__ Sk,
            float* __restrict__ out,
            const int* __restrict__ tE, const int* __restrict__ tS,
            const int* __restrict__ tR, const int* __restrict__ meta) {
    constexpr int NKS  = KD / 32;          // K slices
    constexpr int LOGK = (NKS == 32) ? 5 : (NKS == 16) ? 4 : 3;
    constexpr int ASTR = BM * 32;          // shorts per A slice
    constexpr int NOUT = (MODE == 0) ? 768 : 1024;
    constexpr int WM   = BM / 64;          // 1 or 2
    constexpr int TOT  = COLS_PB * NKS;
    constexpr int BL   = 8192 / (THR * 16);   // B gl_lds per thread per stage (2 or 1)

    const int mt = (MODE == 0) ? blockIdx.x : blockIdx.y;
    if (mt >= meta[MIDX]) return;
    const int e = tE[mt], pos0 = tS[mt], rows = tR[mt];
    const int colbase = (MODE == 0) ? 0 : blockIdx.x * (COLS_PB * 128);
    const int tid = threadIdx.x;
    const int w = tid >> 6, lane = tid & 63, quad = lane >> 4, l15 = lane & 15;
    const int wm = (WM == 2) ? (w & 1) : 0;
    const int wn = (WM == 2) ? (w >> 1) : w;   // 0..3

    __shared__ unsigned short Ares[NKS * ASTR];   // 64 or 128 KB
    __shared__ unsigned short Bs[3][128 * 32];    // 24 KB

    const int r0 = tid >> 2;
    // pre-swizzled global chunk: chunk' = (tid&3) ^ ((r0>>1)&3)
    const int c8s = ((tid & 3) ^ ((tid >> 3) & 3)) * 8;
    const unsigned short* ga  = A + (size_t)(pos0 + r0) * KD + c8s;
    const unsigned short* gbb = Bw + ((size_t)e * NOUT + colbase + r0) * KD + c8s;

    // fragment read offsets with matching XOR swizzle
    const int sq = (quad ^ ((l15 >> 1) & 3)) * 8;
    int aoff[4], boff[2];
    #pragma unroll
    for (int i = 0; i < 4; i++) aoff[i] = (wm * 64 + i * 16 + l15) * 32 + sq;
    #pragma unroll
    for (int j = 0; j < 2; j++) boff[j] = (wn * 32 + j * 16 + l15) * 32 + sq;

    // one B chunk (128 x 32) stage: THR*16B per load; rows r0 (+64 if BL==2)
    #define STAGE_B(buf, s) do { \
        int cc_ = (s) >> LOGK, ks_ = (s) & (NKS - 1); \
        const unsigned short* p_ = gbb + (size_t)cc_ * (128 * KD) + ks_ * 32; \
        gl_lds16(p_, Bs[buf] + w * 512); \
        if (BL == 2) gl_lds16(p_ + (size_t)64 * KD, Bs[buf] + 2048 + w * 512); \
    } while (0)

    // prologue: A resident (one gl_lds per slice per thread) + B stages 0,1
    #pragma unroll
    for (int s = 0; s < NKS; s++)
        gl_lds16(ga + s * 32, Ares + s * ASTR + w * 512);
    STAGE_B(0, 0);
    STAGE_B(1, 1);
    asm volatile("s_waitcnt vmcnt(0)" ::: "memory");
    __builtin_amdgcn_s_barrier();

    floatx4 acc[4][2] = {};

    #pragma unroll 1
    for (int s = 0; s < TOT; s++) {
        const int ks = s & (NKS - 1);
        const int buf = s % 3;
        if (s > 1) {
            if (s < TOT - 1) {
                if (BL == 2) asm volatile("s_waitcnt vmcnt(2)" ::: "memory");
                else         asm volatile("s_waitcnt vmcnt(1)" ::: "memory");
            } else {
                asm volatile("s_waitcnt vmcnt(0)" ::: "memory");
            }
        }
        __builtin_amdgcn_s_barrier();          // stage(s) landed for all waves;
        asm volatile("" ::: "memory");         // prior reads drained (lgkm0 below)
        if (s + 2 < TOT) STAGE_B((s + 2) % 3, s + 2);
        short8 af[4], bf[2];
        #pragma unroll
        for (int i = 0; i < 4; i++) af[i] = *(const short8*)(Ares + ks * ASTR + aoff[i]);
        #pragma unroll
        for (int j = 0; j < 2; j++) bf[j] = *(const short8*)(Bs[buf] + boff[j]);
        #pragma unroll
        for (int i = 0; i < 4; i++)
            #pragma unroll
            for (int j = 0; j < 2; j++)
                acc[i][j] = __builtin_amdgcn_mfma_f32_16x16x32_bf16(af[i], bf[j], acc[i][j], 0, 0, 0);
        asm volatile("s_waitcnt lgkmcnt(0)" ::: "memory");
        __builtin_amdgcn_sched_barrier(0);

        if (ks == NKS - 1) {
            // epilogue for column chunk cc, then reset acc
            const int cc = s >> LOGK;
            const int col0 = colbase + cc * 128;
            #pragma unroll
            for (int i = 0; i < 4; i++) {
                #pragma unroll
                for (int r = 0; r < 4; r++) {
                    int m = wm * 64 + i * 16 + quad * 4 + r;
                    if (m >= rows) continue;
                    size_t row = (size_t)(pos0 + m);
                    if (MODE == 0) {
                        if (col0 < 256) {
                            #pragma unroll
                            for (int j = 0; j < 2; j++) {
                                int n = col0 + wn * 32 + j * 16 + l15;
                                Ub[row * 256 + n] = (half_t)acc[i][j][r];
                            }
                        } else {
                            #pragma unroll
                            for (int j = 0; j < 2; j++) {
                                int n = col0 - 256 + wn * 32 + j * 16 + l15;
                                float v = acc[i][j][r];
                                SHb[row * 512 + n] = f2bf(v * sigm(v));
                            }
                        }
                    } else if (MODE == 1) {
                        int region = col0 >> 8;  // uniform per chunk
                        #pragma unroll
                        for (int j = 0; j < 2; j++) {
                            int n0 = (col0 & 255) + wn * 32 + j * 16 + l15;
                            size_t idx = row * 256 + (size_t)n0;
                            float v = acc[i][j][r];
                            if (region == 0) {
                                Aa[idx] = (half_t)sigm(v);
                            } else if (region == 1) {
                                Wg[idx] = (half_t)(ftanh(v) * (float)Ub[idx]);
                            } else if (region == 2) {
                                Cc[idx] = (half_t)ftanh(v);
                            } else {
                                Sk[idx] = (half_t)(dparam[e * 256 + n0] * sigm(v) * (float)Ub[idx]);
                            }
                        }
                    } else {
                        int tok = perm[row];
                        #pragma unroll
                        for (int j = 0; j < 2; j++) {
                            int n = col0 + wn * 32 + j * 16 + l15;
                            out[(size_t)tok * 1024 + n] = acc[i][j][r];
                        }
                    }
                }
            }
            #pragma unroll
            for (int i = 0; i < 4; i++)
                #pragma unroll
                for (int j = 0; j < 2; j++)
                    acc[i][j] = (floatx4){0.0f, 0.0f, 0.0f, 0.0f};
        }
    }
    #undef STAGE_B
}

// ---------------- K8a: chunk-local affine composition ----------------
__global__ void k_scanA(const half_t* __restrict__ Aa, const half_t* __restrict__ Wg,
                        const int* __restrict__ cStart, const int* __restrict__ cLen,
                        const int* __restrict__ meta,
                        float* __restrict__ SA, float* __restrict__ SQ) {
    int id = blockIdx.x;
    if (id >= meta[1]) return;
    int t = threadIdx.x;
    int s0 = cStart[id], L = cLen[id];
    size_t idx = (size_t)s0 * 256 + t;
    float p = 1.0f, q = 0.0f;
    for (int i = 0; i < L; i++) {
        float a = (float)Aa[idx], ww = (float)Wg[idx];
        q = a * q + ww;
        p *= a;
        idx += 256;
    }
    SA[(size_t)id * 256 + t] = p;
    SQ[(size_t)id * 256 + t] = q;
}

// ---------------- K8b: per-group serial combine -> chunk h_in ----------------
__global__ void k_scanB(const float* __restrict__ SA, const float* __restrict__ SQ,
                        const int* __restrict__ gBase, const int* __restrict__ cnt,
                        float* __restrict__ Hin) {
    int g = blockIdx.x, t = threadIdx.x;
    int base = gBase[g], nch = (cnt[g] + CHUNK - 1) / CHUNK;
    float h = 0.0f;
    for (int c = 0; c < nch; c++) {
        size_t k = (size_t)(base + c) * 256 + t;
        Hin[k] = h;
        h = SA[k] * h + SQ[k];
    }
}

// ---------------- K8c: re-scan with h_in, emit y (bf16) ----------------
__global__ void k_scanC(const half_t* __restrict__ Aa, const half_t* __restrict__ Wg,
                        const half_t* __restrict__ Cc, const half_t* __restrict__ Sk,
                        const int* __restrict__ cStart, const int* __restrict__ cLen,
                        const int* __restrict__ meta, const float* __restrict__ Hin,
                        unsigned short* __restrict__ Yb) {
    int id = blockIdx.x;
    if (id >= meta[1]) return;
    int t = threadIdx.x;
    int s0 = cStart[id], L = cLen[id];
    float h = Hin[(size_t)id * 256 + t];
    size_t idx = (size_t)s0 * 256 + t;
    for (int i = 0; i < L; i++) {
        float a = (float)Aa[idx], ww = (float)Wg[idx];
        float c = (float)Cc[idx], sk = (float)Sk[idx];
        h = a * h + ww;
        Yb[idx] = f2bf(c * h + sk);
        idx += 256;
    }
}

extern "C" void kernel_launch(void* const* d_in, const int* in_sizes, int n_in,
                              void* d_out, int out_size, void* d_ws, size_t ws_size,
                              hipStream_t stream) {
    const float* xin   = (const float*)d_in[0];
    const int*   tok   = (const int*)d_in[1];
    const float* Win   = (const float*)d_in[2];
    const float* Wsin  = (const float*)d_in[3];
    const float* Wsout = (const float*)d_in[4];
    const float* Wout  = (const float*)d_in[5];
    const float* dpar  = (const float*)d_in[6];
    float* out = (float*)d_out;

    size_t off = 0;
    char* base = (char*)d_ws;
    auto alloc = [&](size_t bytes) -> void* {
        void* p = base + off;
        off += (bytes + 255) & ~(size_t)255;
        return p;
    };
    half_t*         Ub  = (half_t*)alloc((size_t)RPAD * NN * 2);
    unsigned short* SHb = (unsigned short*)alloc((size_t)RPAD * HH * 2);
    unsigned short* Xs  = (unsigned short*)alloc((size_t)RPAD * DD * 2);
    unsigned short* Yb  = (unsigned short*)alloc((size_t)RPAD * NN * 2);
    half_t* Aa = (half_t*)alloc((size_t)TOKS * NN * 2);
    half_t* Wg = (half_t*)alloc((size_t)TOKS * NN * 2);
    half_t* Cc = (half_t*)alloc((size_t)TOKS * NN * 2);
    half_t* Sk = (half_t*)alloc((size_t)TOKS * NN * 2);
    unsigned short* W12 = (unsigned short*)alloc((size_t)8 * 768 * 1024 * 2);
    unsigned short* Wso = (unsigned short*)alloc((size_t)8 * 1024 * 512 * 2);
    unsigned short* Wo  = (unsigned short*)alloc((size_t)8 * 1024 * 256 * 2);
    float* SA  = (float*)alloc((size_t)MAXCHUNKS * 256 * 4);
    float* SQ  = (float*)alloc((size_t)MAXCHUNKS * 256 * 4);
    float* Hin = (float*)alloc((size_t)MAXCHUNKS * 256 * 4);
    int* perm   = (int*)alloc(TOKS * 4);
    int* cnt    = (int*)alloc(64 * 4);
    int* grpoff = (int*)alloc(64 * 4);
    int* tileE  = (int*)alloc(MAXTILES * 4);
    int* tileS  = (int*)alloc(MAXTILES * 4);
    int* tileR  = (int*)alloc(MAXTILES * 4);
    int* tE64   = (int*)alloc(MAXT64 * 4);
    int* tS64   = (int*)alloc(MAXT64 * 4);
    int* tR64   = (int*)alloc(MAXT64 * 4);
    int* cGrp   = (int*)alloc(MAXCHUNKS * 4);
    int* cStart = (int*)alloc(MAXCHUNKS * 4);
    int* cLen   = (int*)alloc(MAXCHUNKS * 4);
    int* gBase  = (int*)alloc(64 * 4);
    int* meta   = (int*)alloc(16 * 4);

    k_route<<<8, 256, 0, stream>>>(tok, cnt);
    k_offsets<<<1, 256, 0, stream>>>(cnt, grpoff, tileE, tileS, tileR,
                                     tE64, tS64, tR64,
                                     cGrp, cStart, cLen, gBase, meta);
    k_scatter<<<8, 256, 0, stream>>>(tok, grpoff, perm);
    k_cvtw<<<12288, 256, 0, stream>>>(Win, Wsin, Wsout, Wout, W12, Wso, Wo);
    k_gather<<<RPAD, 256, 0, stream>>>(xin, perm, Xs, SHb, Yb);

    // MODE 0: BM=64, 256 thr, 6 col chunks (768), tiles64, LDS 152KB
    k_mfma<0, 1024, 64, 256, 6, 2, 1><<<MAXT64, 256, 0, stream>>>(
        Xs, W12, perm, dpar, Ub, SHb, Aa, Wg, Cc, Sk, out, tE64, tS64, tR64, meta);
    // MODE 1: BM=128, 512 thr, 2 col-halves x 4 chunks, tiles128, LDS 152KB
    k_mfma<1, 512, 128, 512, 4, 0, 2><<<dim3(2, MAXTILES), 512, 0, stream>>>(
        SHb, Wso, perm, dpar, Ub, SHb, Aa, Wg, Cc, Sk, out, tileE, tileS, tileR, meta);

    k_scanA<<<MAXCHUNKS, 256, 0, stream>>>(Aa, Wg, cStart, cLen, meta, SA, SQ);
    k_scanB<<<64, 256, 0, stream>>>(SA, SQ, gBase, cnt, Hin);
    k_scanC<<<MAXCHUNKS, 256, 0, stream>>>(Aa, Wg, Cc, Sk, cStart, cLen, meta, Hin, Yb);

    // MODE 2: BM=128, 512 thr, 2 col-halves x 4 chunks, tiles128, LDS 88KB
    k_mfma<2, 256, 128, 512, 4, 0, 2><<<dim3(2, MAXTILES), 512, 0, stream>>>(
        Yb, Wo, perm, dpar, Ub, SHb, Aa, Wg, Cc, Sk, out, tileE, tileS, tileR, meta);
}

// Round 7
// 504.073 us; speedup vs baseline: 1.2293x; 1.2293x over previous
//
#include <hip/hip_runtime.h>

// HashRoutedSSMLayer: B=8,S=2048,D=1024,N=256,H=512,E=8 — fp32 in/out.
// Round 11: fix round-10's staging bug — second 128-row pass lands at
// half-buffer offset 4096 shorts (128 rows x 32), NOT 8192 (which wrote past
// the 8192-short buffer into the next one and left rows 128-255 unstaged).
// Design unchanged: 256x256 tile grouped GEMM, 512 thr / 8 waves (2M x 4N,
// per-wave 128x64, acc[8][4]); BK=32; 3-buf 1-barrier counted-vmcnt skeleton;
// 96KB LDS -> 1 block/CU x 8 waves = 2 waves/SIMD; 256-row tile table.

#define TOKS 16384
#define RPAD 16640      // TOKS + 256 pad rows for 256-row tile overread
#define DD   1024
#define NN   256
#define HH   512
#define MAXT256   72    // sum ceil(ce/256) <= 64+8
#define MAXCHUNKS 1088  // sum ceil(n_g/16) <= 1024+64
#define CHUNK 16

typedef short short8 __attribute__((ext_vector_type(8)));
typedef float floatx4 __attribute__((ext_vector_type(4)));
typedef _Float16 half_t;

#define AS_GLOBAL __attribute__((address_space(1)))
#define AS_LDS    __attribute__((address_space(3)))

__device__ __forceinline__ void gl_lds16(const void* g, void* l) {
    __builtin_amdgcn_global_load_lds((const AS_GLOBAL void*)g, (AS_LDS void*)l, 16, 0, 0);
}

__device__ __forceinline__ unsigned short f2bf(float f) {
    union { float f; unsigned u; } c; c.f = f;
    unsigned r = c.u + 0x7FFF + ((c.u >> 16) & 1);
    return (unsigned short)(r >> 16);
}
__device__ __forceinline__ int route_of(int token) {
    unsigned x = (unsigned)token;
    x ^= x >> 16; x *= 2246822507u; x ^= x >> 13; x *= 3266489909u; x ^= x >> 16;
    return (int)(x & 7u);
}
__device__ __forceinline__ float sigm(float v) { return 1.0f / (1.0f + __expf(-v)); }
__device__ __forceinline__ float ftanh(float v) {
    float e = __expf(2.0f * v);          // inf-safe: v>>0 -> 1, v<<0 -> -1
    return 1.0f - 2.0f / (e + 1.0f);
}

// ---------------- K1: per-row route histogram ----------------
__global__ void k_route(const int* __restrict__ tok, int* __restrict__ cnt) {
    int b = blockIdx.x, tid = threadIdx.x;
    __shared__ int lc[256 * 8];
    #pragma unroll
    for (int e = 0; e < 8; e++) lc[tid * 8 + e] = 0;
    #pragma unroll
    for (int i = 0; i < 8; i++) {
        int e = route_of(tok[b * 2048 + tid * 8 + i]);
        lc[tid * 8 + e]++;
    }
    __syncthreads();
    if (tid < 8) {
        int s = 0;
        for (int t = 0; t < 256; t++) s += lc[t * 8 + tid];
        cnt[b * 8 + tid] = s;
    }
}

// ---------------- K2: offsets + 256-row tile table + chunk table ----------------
__global__ void k_offsets(const int* __restrict__ cnt, int* __restrict__ grpoff,
                          int* __restrict__ tE, int* __restrict__ tS,
                          int* __restrict__ tR,
                          int* __restrict__ cGrp, int* __restrict__ cStart,
                          int* __restrict__ cLen, int* __restrict__ gBase,
                          int* __restrict__ meta) {
    __shared__ int sc[64], ce[8], eoff[9], et[9], gb[65], go[64];
    int tid = threadIdx.x;
    if (tid < 64) sc[tid] = cnt[tid];
    __syncthreads();
    if (tid < 8) { int s = 0; for (int b = 0; b < 8; b++) s += sc[b * 8 + tid]; ce[tid] = s; }
    __syncthreads();
    if (tid == 0) {
        eoff[0] = 0; et[0] = 0;
        for (int e = 0; e < 8; e++) {
            eoff[e + 1] = eoff[e] + ce[e];
            et[e + 1] = et[e] + (ce[e] + 255) / 256;
        }
        meta[0] = et[8];
        gb[0] = 0;
        for (int g = 0; g < 64; g++) gb[g + 1] = gb[g] + (sc[g] + CHUNK - 1) / CHUNK;
        meta[1] = gb[64];
    }
    __syncthreads();
    if (tid < 64) {
        int b = tid >> 3, e = tid & 7;
        int run = eoff[e];
        for (int b2 = 0; b2 < b; b2++) run += sc[b2 * 8 + e];
        go[tid] = run;
        grpoff[tid] = run;
    }
    __syncthreads();
    if (tid < 8) {   // 256-row tiles for expert tid
        int e = tid, st = eoff[e], c = ce[e], t0 = et[e];
        for (int i = 0, k = 0; i < c; i += 256, k++) {
            tE[t0 + k] = e; tS[t0 + k] = st + i;
            tR[t0 + k] = (c - i < 256) ? (c - i) : 256;
        }
    }
    if (tid < 64) {  // chunks for group tid
        int g = tid, n = sc[g], base = gb[g], s0 = go[g];
        gBase[g] = base;
        for (int i = 0, c = 0; i < n; i += CHUNK, c++) {
            cGrp[base + c] = g;
            cStart[base + c] = s0 + i;
            cLen[base + c] = (n - i < CHUNK) ? (n - i) : CHUNK;
        }
    }
}

// ---------------- K3: stable counting-sort scatter ----------------
__global__ void k_scatter(const int* __restrict__ tok, const int* __restrict__ grpoff,
                          int* __restrict__ perm) {
    int b = blockIdx.x, tid = threadIdx.x;
    __shared__ int lh[8 * 256];
    int r[8];
    int myc[8] = {0,0,0,0,0,0,0,0};
    #pragma unroll
    for (int i = 0; i < 8; i++) {
        int e = route_of(tok[b * 2048 + tid * 8 + i]);
        r[i] = e; myc[e]++;
    }
    #pragma unroll
    for (int e = 0; e < 8; e++) lh[e * 256 + tid] = myc[e];
    __syncthreads();
    for (int e = 0; e < 8; e++) {
        for (int off = 1; off < 256; off <<= 1) {
            int add = (tid >= off) ? lh[e * 256 + tid - off] : 0;
            __syncthreads();
            lh[e * 256 + tid] += add;
            __syncthreads();
        }
    }
    int basep[8];
    #pragma unroll
    for (int e = 0; e < 8; e++) basep[e] = grpoff[b * 8 + e] + lh[e * 256 + tid] - myc[e];
    #pragma unroll
    for (int i = 0; i < 8; i++) {
        int e = r[i];
        perm[basep[e]++] = b * 2048 + tid * 8 + i;
    }
}

// ---------------- K4: weights fp32 -> bf16 (W12 = [Win|Wsin] concat) ----------------
__global__ void k_cvtw(const float* __restrict__ Win, const float* __restrict__ Wsin,
                       const float* __restrict__ Wsout, const float* __restrict__ Wout,
                       unsigned short* __restrict__ W12, unsigned short* __restrict__ Wso,
                       unsigned short* __restrict__ Wo) {
    const int C12 = 8 * 768 * 1024 / 4, CSO = 8 * 1024 * 512 / 4, CWO = 8 * 1024 * 256 / 4;
    int c = blockIdx.x * 256 + threadIdx.x;
    float4 v; unsigned short* dst;
    if (c < C12) {
        int d = c * 4;
        int e = d / (768 * 1024);
        int rem = d - e * (768 * 1024);
        int r = rem >> 10, k = rem & 1023;
        const float* src = (r < 256) ? (Win + (((size_t)e * 256 + r) << 10) + k)
                                     : (Wsin + (((size_t)e * 512 + (r - 256)) << 10) + k);
        v = *(const float4*)src;
        dst = W12 + d;
    } else if (c < C12 + CSO) {
        int d = (c - C12) * 4;
        v = *(const float4*)(Wsout + d);
        dst = Wso + d;
    } else if (c < C12 + CSO + CWO) {
        int d = (c - C12 - CSO) * 4;
        v = *(const float4*)(Wout + d);
        dst = Wo + d;
    } else return;
    ushort4 o;
    o.x = f2bf(v.x); o.y = f2bf(v.y); o.z = f2bf(v.z); o.w = f2bf(v.w);
    *(ushort4*)dst = o;
}

// ---------------- K5: gather x into sorted bf16 rows + zero pads ----------------
__global__ void k_gather(const float* __restrict__ x, const int* __restrict__ perm,
                         unsigned short* __restrict__ Xs, unsigned short* __restrict__ SHb,
                         unsigned short* __restrict__ Yb) {
    int r = blockIdx.x, t = threadIdx.x;
    if (r < TOKS) {
        int tok = perm[r];
        float4 v = *(const float4*)(x + (size_t)tok * 1024 + t * 4);
        ushort4 o;
        o.x = f2bf(v.x); o.y = f2bf(v.y); o.z = f2bf(v.z); o.w = f2bf(v.w);
        *(ushort4*)(Xs + (size_t)r * 1024 + t * 4) = o;
    } else {
        ushort4 z = {0, 0, 0, 0};
        *(ushort4*)(Xs + (size_t)r * 1024 + t * 4) = z;
        if (t < 128) *(ushort4*)(SHb + (size_t)r * 512 + t * 4) = z;
        if (t < 64)  *(ushort4*)(Yb + (size_t)r * 256 + t * 4) = z;
    }
}

// ---------------- MFMA grouped GEMM, BM=256 BN=256 BK=32, 3-buf pipeline ----------------
// MODE 0: A=Xs (K=1024), B=W12 [e][768][1024]: col0==0 -> Ub fp16; else silu -> SHb
// MODE 1: A=SHb (K=512), B=Wso [e][1024][512]: region col0>>8 -> fp16 gates
// MODE 2: A=Yb (K=256),  B=Wo  [e][1024][256]: scatter fp32 out via perm
// 512 thr, 8 waves 2Mx4N; per-wave 128x64 out (acc[8][4]); 12 ds_read_b128 +
// 32 MFMA per wave-step; 4 gl_lds/thread/step; LDS 3x(16+16)KB = 96KB.
template<int MODE, int KD>
__global__ __launch_bounds__(512, 2)
void k_mfma(const unsigned short* __restrict__ A, const unsigned short* __restrict__ Bw,
            const int* __restrict__ perm, const float* __restrict__ dparam,
            half_t* __restrict__ Ub, unsigned short* __restrict__ SHb,
            half_t* __restrict__ Aa, half_t* __restrict__ Wg,
            half_t* __restrict__ Cc, half_t* __restrict__ Sk,
            float* __restrict__ out,
            const int* __restrict__ tE, const int* __restrict__ tS,
            const int* __restrict__ tR, const int* __restrict__ meta) {
    const int mt = blockIdx.x;
    if (mt >= meta[0]) return;
    const int e = tE[mt], pos0 = tS[mt], rows = tR[mt];
    const int col0 = blockIdx.y * 256;
    const int tid = threadIdx.x;
    const int w = tid >> 6, lane = tid & 63, quad = lane >> 4, l15 = lane & 15;
    const int wm = w & 1, wn = w >> 1;          // 2M x 4N wave grid
    constexpr int NOUT = (MODE == 0) ? 768 : 1024;
    constexpr int NK = KD / 32;

    // [3][256 rows][32 K] bf16 per operand: 16KB/buf, 96KB total
    __shared__ unsigned short As[3][256 * 32];
    __shared__ unsigned short Bs[3][256 * 32];

    const int r0 = tid >> 2;                    // 0..127 (pass 1 rows)
    // pre-swizzled global chunk: chunk' = (tid&3) ^ ((row>>1)&3); key identical
    // for pass-2 rows (+128: (row>>1)&3 unchanged mod 4).
    const int c8s = ((tid & 3) ^ ((tid >> 3) & 3)) * 8;
    const unsigned short* ga = A + (size_t)(pos0 + r0) * KD + c8s;
    const unsigned short* gb = Bw + ((size_t)e * NOUT + col0 + r0) * KD + c8s;

    // fragment read offsets, matching XOR swizzle (row bases all 0 mod 16)
    const int sq = (quad ^ ((l15 >> 1) & 3)) * 8;
    int aoff[8], boff[4];
    #pragma unroll
    for (int i = 0; i < 8; i++) aoff[i] = (wm * 128 + i * 16 + l15) * 32 + sq;
    #pragma unroll
    for (int j = 0; j < 4; j++) boff[j] = (wn * 64 + j * 16 + l15) * 32 + sq;

    floatx4 acc[8][4] = {};

    // stage one BK=32 tile: 2 passes of 128 rows per operand (4 gl_lds/thread)
    // pass-2 dest = +4096 shorts (128 rows x 32) — HALF the 8192-short buffer.
    #define STAGE(buf, k0) do { \
        gl_lds16(ga + (k0),                     As[buf] + w * 512); \
        gl_lds16(ga + (size_t)128 * KD + (k0),  As[buf] + 4096 + w * 512); \
        gl_lds16(gb + (k0),                     Bs[buf] + w * 512); \
        gl_lds16(gb + (size_t)128 * KD + (k0),  Bs[buf] + 4096 + w * 512); \
    } while (0)

    STAGE(0, 0);                      // 4 outstanding
    STAGE(1, 32);                     // 8 outstanding
    int cur = 0, pre = 2;
    for (int kt = 0; kt < NK; kt++) {
        if (kt < NK - 1) {
            asm volatile("s_waitcnt vmcnt(4)" ::: "memory");   // stage(kt) landed
        } else {
            asm volatile("s_waitcnt vmcnt(0)" ::: "memory");
        }
        __builtin_amdgcn_s_barrier();          // all waves' stage(kt) landed; prev reads drained
        asm volatile("" ::: "memory");
        if (kt + 2 < NK) STAGE(pre, (kt + 2) * 32);   // 2-deep prefetch, distinct buffer
        short8 af[8], bf[4];
        #pragma unroll
        for (int i = 0; i < 8; i++) af[i] = *(const short8*)(As[cur] + aoff[i]);
        #pragma unroll
        for (int j = 0; j < 4; j++) bf[j] = *(const short8*)(Bs[cur] + boff[j]);
        #pragma unroll
        for (int i = 0; i < 8; i++)
            #pragma unroll
            for (int j = 0; j < 4; j++)
                acc[i][j] = __builtin_amdgcn_mfma_f32_16x16x32_bf16(af[i], bf[j], acc[i][j], 0, 0, 0);
        asm volatile("s_waitcnt lgkmcnt(0)" ::: "memory");
        __builtin_amdgcn_sched_barrier(0);
        cur = (cur == 2) ? 0 : cur + 1;
        pre = (pre == 2) ? 0 : pre + 1;
    }
    #undef STAGE
    asm volatile("" ::: "memory");             // keep epilogue loads out of the loop

    // epilogue: per 16x16 tile, col = l15, row = quad*4 + reg
    #pragma unroll
    for (int i = 0; i < 8; i++) {
        #pragma unroll
        for (int r = 0; r < 4; r++) {
            int m = wm * 128 + i * 16 + quad * 4 + r;
            if (m >= rows) continue;
            size_t row = (size_t)(pos0 + m);
            if (MODE == 0) {
                if (col0 == 0) {
                    #pragma unroll
                    for (int j = 0; j < 4; j++) {
                        int n = wn * 64 + j * 16 + l15;
                        Ub[row * 256 + n] = (half_t)acc[i][j][r];
                    }
                } else {
                    #pragma unroll
                    for (int j = 0; j < 4; j++) {
                        int n = col0 - 256 + wn * 64 + j * 16 + l15;
                        float v = acc[i][j][r];
                        SHb[row * 512 + n] = f2bf(v * sigm(v));
                    }
                }
            } else if (MODE == 1) {
                int region = col0 >> 8;  // 0..3, block-uniform (BN==256==region)
                #pragma unroll
                for (int j = 0; j < 4; j++) {
                    int n0 = wn * 64 + j * 16 + l15;
                    size_t idx = row * 256 + (size_t)n0;
                    float v = acc[i][j][r];
                    if (region == 0) {
                        Aa[idx] = (half_t)sigm(v);
                    } else if (region == 1) {
                        Wg[idx] = (half_t)(ftanh(v) * (float)Ub[idx]);
                    } else if (region == 2) {
                        Cc[idx] = (half_t)ftanh(v);
                    } else {
                        Sk[idx] = (half_t)(dparam[e * 256 + n0] * sigm(v) * (float)Ub[idx]);
                    }
                }
            } else {
                int tok = perm[row];
                #pragma unroll
                for (int j = 0; j < 4; j++) {
                    int n = col0 + wn * 64 + j * 16 + l15;
                    out[(size_t)tok * 1024 + n] = acc[i][j][r];
                }
            }
        }
    }
}

// ---------------- K8a: chunk-local affine composition ----------------
__global__ void k_scanA(const half_t* __restrict__ Aa, const half_t* __restrict__ Wg,
                        const int* __restrict__ cStart, const int* __restrict__ cLen,
                        const int* __restrict__ meta,
                        float* __restrict__ SA, float* __restrict__ SQ) {
    int id = blockIdx.x;
    if (id >= meta[1]) return;
    int t = threadIdx.x;
    int s0 = cStart[id], L = cLen[id];
    size_t idx = (size_t)s0 * 256 + t;
    float p = 1.0f, q = 0.0f;
    for (int i = 0; i < L; i++) {
        float a = (float)Aa[idx], ww = (float)Wg[idx];
        q = a * q + ww;
        p *= a;
        idx += 256;
    }
    SA[(size_t)id * 256 + t] = p;
    SQ[(size_t)id * 256 + t] = q;
}

// ---------------- K8b: per-group serial combine -> chunk h_in ----------------
__global__ void k_scanB(const float* __restrict__ SA, const float* __restrict__ SQ,
                        const int* __restrict__ gBase, const int* __restrict__ cnt,
                        float* __restrict__ Hin) {
    int g = blockIdx.x, t = threadIdx.x;
    int base = gBase[g], nch = (cnt[g] + CHUNK - 1) / CHUNK;
    float h = 0.0f;
    for (int c = 0; c < nch; c++) {
        size_t k = (size_t)(base + c) * 256 + t;
        Hin[k] = h;
        h = SA[k] * h + SQ[k];
    }
}

// ---------------- K8c: re-scan with h_in, emit y (bf16) ----------------
__global__ void k_scanC(const half_t* __restrict__ Aa, const half_t* __restrict__ Wg,
                        const half_t* __restrict__ Cc, const half_t* __restrict__ Sk,
                        const int* __restrict__ cStart, const int* __restrict__ cLen,
                        const int* __restrict__ meta, const float* __restrict__ Hin,
                        unsigned short* __restrict__ Yb) {
    int id = blockIdx.x;
    if (id >= meta[1]) return;
    int t = threadIdx.x;
    int s0 = cStart[id], L = cLen[id];
    float h = Hin[(size_t)id * 256 + t];
    size_t idx = (size_t)s0 * 256 + t;
    for (int i = 0; i < L; i++) {
        float a = (float)Aa[idx], ww = (float)Wg[idx];
        float c = (float)Cc[idx], sk = (float)Sk[idx];
        h = a * h + ww;
        Yb[idx] = f2bf(c * h + sk);
        idx += 256;
    }
}

extern "C" void kernel_launch(void* const* d_in, const int* in_sizes, int n_in,
                              void* d_out, int out_size, void* d_ws, size_t ws_size,
                              hipStream_t stream) {
    const float* xin   = (const float*)d_in[0];
    const int*   tok   = (const int*)d_in[1];
    const float* Win   = (const float*)d_in[2];
    const float* Wsin  = (const float*)d_in[3];
    const float* Wsout = (const float*)d_in[4];
    const float* Wout  = (const float*)d_in[5];
    const float* dpar  = (const float*)d_in[6];
    float* out = (float*)d_out;

    size_t off = 0;
    char* base = (char*)d_ws;
    auto alloc = [&](size_t bytes) -> void* {
        void* p = base + off;
        off += (bytes + 255) & ~(size_t)255;
        return p;
    };
    half_t*         Ub  = (half_t*)alloc((size_t)RPAD * NN * 2);
    unsigned short* SHb = (unsigned short*)alloc((size_t)RPAD * HH * 2);
    unsigned short* Xs  = (unsigned short*)alloc((size_t)RPAD * DD * 2);
    unsigned short* Yb  = (unsigned short*)alloc((size_t)RPAD * NN * 2);
    half_t* Aa = (half_t*)alloc((size_t)TOKS * NN * 2);
    half_t* Wg = (half_t*)alloc((size_t)TOKS * NN * 2);
    half_t* Cc = (half_t*)alloc((size_t)TOKS * NN * 2);
    half_t* Sk = (half_t*)alloc((size_t)TOKS * NN * 2);
    unsigned short* W12 = (unsigned short*)alloc((size_t)8 * 768 * 1024 * 2);
    unsigned short* Wso = (unsigned short*)alloc((size_t)8 * 1024 * 512 * 2);
    unsigned short* Wo  = (unsigned short*)alloc((size_t)8 * 1024 * 256 * 2);
    float* SA  = (float*)alloc((size_t)MAXCHUNKS * 256 * 4);
    float* SQ  = (float*)alloc((size_t)MAXCHUNKS * 256 * 4);
    float* Hin = (float*)alloc((size_t)MAXCHUNKS * 256 * 4);
    int* perm   = (int*)alloc(TOKS * 4);
    int* cnt    = (int*)alloc(64 * 4);
    int* grpoff = (int*)alloc(64 * 4);
    int* tE     = (int*)alloc(MAXT256 * 4);
    int* tS     = (int*)alloc(MAXT256 * 4);
    int* tR     = (int*)alloc(MAXT256 * 4);
    int* cGrp   = (int*)alloc(MAXCHUNKS * 4);
    int* cStart = (int*)alloc(MAXCHUNKS * 4);
    int* cLen   = (int*)alloc(MAXCHUNKS * 4);
    int* gBase  = (int*)alloc(64 * 4);
    int* meta   = (int*)alloc(16 * 4);

    k_route<<<8, 256, 0, stream>>>(tok, cnt);
    k_offsets<<<1, 256, 0, stream>>>(cnt, grpoff, tE, tS, tR,
                                     cGrp, cStart, cLen, gBase, meta);
    k_scatter<<<8, 256, 0, stream>>>(tok, grpoff, perm);
    k_cvtw<<<12288, 256, 0, stream>>>(Win, Wsin, Wsout, Wout, W12, Wso, Wo);
    k_gather<<<RPAD, 256, 0, stream>>>(xin, perm, Xs, SHb, Yb);

    k_mfma<0, 1024><<<dim3(MAXT256, 3), 512, 0, stream>>>(Xs, W12, perm, dpar,
        Ub, SHb, Aa, Wg, Cc, Sk, out, tE, tS, tR, meta);
    k_mfma<1, 512><<<dim3(MAXT256, 4), 512, 0, stream>>>(SHb, Wso, perm, dpar,
        Ub, SHb, Aa, Wg, Cc, Sk, out, tE, tS, tR, meta);

    k_scanA<<<MAXCHUNKS, 256, 0, stream>>>(Aa, Wg, cStart, cLen, meta, SA, SQ);
    k_scanB<<<64, 256, 0, stream>>>(SA, SQ, gBase, cnt, Hin);
    k_scanC<<<MAXCHUNKS, 256, 0, stream>>>(Aa, Wg, Cc, Sk, cStart, cLen, meta, Hin, Yb);

    k_mfma<2, 256><<<dim3(MAXT256, 4), 512, 0, stream>>>(Yb, Wo, perm, dpar,
        Ub, SHb, Aa, Wg, Cc, Sk, out, tE, tS, tR, meta);
}

// Round 8
// 341.404 us; speedup vs baseline: 1.8150x; 1.4765x over previous
//
#include <hip/hip_runtime.h>

// HashRoutedSSMLayer: B=8,S=2048,D=1024,N=256,H=512,E=8 — fp32 in/out.
// Round 12: revert to round-8 champion skeleton (128-row tiles, 3-buf BK=32,
// 2-deep prefetch, 1 barrier/step) with BN 128->64: LDS 48->36KB -> 4 blocks/CU
// (vs 3). Empirical law from rounds 0-11: mode-1 dur tracks blocks/CU
// (1blk: 206-244us, 3blk: 67.7, 5blk: 72.5) — short-K blocks live in a ~7k
// cycle/step latency stall that only co-resident blocks hide. 256²/8-phase
// (1 blk/CU) and A-resident (1 blk/CU) both failed on this law.
// NJ=2 wave mapping (wn*32, acc[4][2]) verified correct in round-9 bench.

#define TOKS 16384
#define RPAD 16512      // TOKS + 128 pad rows for tile overread
#define DD   1024
#define NN   256
#define HH   512
#define MAXTILES  136   // sum ceil(ce/128) <= 128+8
#define MAXCHUNKS 1088  // sum ceil(n_g/16) <= 1024+64
#define CHUNK 16

typedef short short8 __attribute__((ext_vector_type(8)));
typedef float floatx4 __attribute__((ext_vector_type(4)));
typedef _Float16 half_t;

#define AS_GLOBAL __attribute__((address_space(1)))
#define AS_LDS    __attribute__((address_space(3)))

__device__ __forceinline__ void gl_lds16(const void* g, void* l) {
    __builtin_amdgcn_global_load_lds((const AS_GLOBAL void*)g, (AS_LDS void*)l, 16, 0, 0);
}

__device__ __forceinline__ unsigned short f2bf(float f) {
    union { float f; unsigned u; } c; c.f = f;
    unsigned r = c.u + 0x7FFF + ((c.u >> 16) & 1);
    return (unsigned short)(r >> 16);
}
__device__ __forceinline__ int route_of(int token) {
    unsigned x = (unsigned)token;
    x ^= x >> 16; x *= 2246822507u; x ^= x >> 13; x *= 3266489909u; x ^= x >> 16;
    return (int)(x & 7u);
}
__device__ __forceinline__ float sigm(float v) { return 1.0f / (1.0f + __expf(-v)); }
__device__ __forceinline__ float ftanh(float v) {
    float e = __expf(2.0f * v);          // inf-safe: v>>0 -> 1, v<<0 -> -1
    return 1.0f - 2.0f / (e + 1.0f);
}

// ---------------- K1: per-row route histogram ----------------
__global__ void k_route(const int* __restrict__ tok, int* __restrict__ cnt) {
    int b = blockIdx.x, tid = threadIdx.x;
    __shared__ int lc[256 * 8];
    #pragma unroll
    for (int e = 0; e < 8; e++) lc[tid * 8 + e] = 0;
    #pragma unroll
    for (int i = 0; i < 8; i++) {
        int e = route_of(tok[b * 2048 + tid * 8 + i]);
        lc[tid * 8 + e]++;
    }
    __syncthreads();
    if (tid < 8) {
        int s = 0;
        for (int t = 0; t < 256; t++) s += lc[t * 8 + tid];
        cnt[b * 8 + tid] = s;
    }
}

// ---------------- K2: offsets + tile table + chunk table ----------------
__global__ void k_offsets(const int* __restrict__ cnt, int* __restrict__ grpoff,
                          int* __restrict__ tileE, int* __restrict__ tileS,
                          int* __restrict__ tileR,
                          int* __restrict__ cGrp, int* __restrict__ cStart,
                          int* __restrict__ cLen, int* __restrict__ gBase,
                          int* __restrict__ meta) {
    __shared__ int sc[64], ce[8], eoff[9], etile[9], gb[65], go[64];
    int tid = threadIdx.x;
    if (tid < 64) sc[tid] = cnt[tid];
    __syncthreads();
    if (tid < 8) { int s = 0; for (int b = 0; b < 8; b++) s += sc[b * 8 + tid]; ce[tid] = s; }
    __syncthreads();
    if (tid == 0) {
        eoff[0] = 0; etile[0] = 0;
        for (int e = 0; e < 8; e++) {
            eoff[e + 1] = eoff[e] + ce[e];
            etile[e + 1] = etile[e] + (ce[e] + 127) / 128;
        }
        meta[0] = etile[8];
        gb[0] = 0;
        for (int g = 0; g < 64; g++) gb[g + 1] = gb[g] + (sc[g] + CHUNK - 1) / CHUNK;
        meta[1] = gb[64];
    }
    __syncthreads();
    if (tid < 64) {
        int b = tid >> 3, e = tid & 7;
        int run = eoff[e];
        for (int b2 = 0; b2 < b; b2++) run += sc[b2 * 8 + e];
        go[tid] = run;
        grpoff[tid] = run;
    }
    __syncthreads();
    if (tid < 8) {   // tiles for expert tid
        int e = tid, st = eoff[e], c = ce[e], t0 = etile[e];
        for (int i = 0, k = 0; i < c; i += 128, k++) {
            tileE[t0 + k] = e; tileS[t0 + k] = st + i;
            tileR[t0 + k] = (c - i < 128) ? (c - i) : 128;
        }
    }
    if (tid < 64) {  // chunks for group tid
        int g = tid, n = sc[g], base = gb[g], s0 = go[g];
        gBase[g] = base;
        for (int i = 0, c = 0; i < n; i += CHUNK, c++) {
            cGrp[base + c] = g;
            cStart[base + c] = s0 + i;
            cLen[base + c] = (n - i < CHUNK) ? (n - i) : CHUNK;
        }
    }
}

// ---------------- K3: stable counting-sort scatter ----------------
__global__ void k_scatter(const int* __restrict__ tok, const int* __restrict__ grpoff,
                          int* __restrict__ perm) {
    int b = blockIdx.x, tid = threadIdx.x;
    __shared__ int lh[8 * 256];
    int r[8];
    int myc[8] = {0,0,0,0,0,0,0,0};
    #pragma unroll
    for (int i = 0; i < 8; i++) {
        int e = route_of(tok[b * 2048 + tid * 8 + i]);
        r[i] = e; myc[e]++;
    }
    #pragma unroll
    for (int e = 0; e < 8; e++) lh[e * 256 + tid] = myc[e];
    __syncthreads();
    for (int e = 0; e < 8; e++) {
        for (int off = 1; off < 256; off <<= 1) {
            int add = (tid >= off) ? lh[e * 256 + tid - off] : 0;
            __syncthreads();
            lh[e * 256 + tid] += add;
            __syncthreads();
        }
    }
    int basep[8];
    #pragma unroll
    for (int e = 0; e < 8; e++) basep[e] = grpoff[b * 8 + e] + lh[e * 256 + tid] - myc[e];
    #pragma unroll
    for (int i = 0; i < 8; i++) {
        int e = r[i];
        perm[basep[e]++] = b * 2048 + tid * 8 + i;
    }
}

// ---------------- K4: weights fp32 -> bf16 (W12 = [Win|Wsin] concat) ----------------
__global__ void k_cvtw(const float* __restrict__ Win, const float* __restrict__ Wsin,
                       const float* __restrict__ Wsout, const float* __restrict__ Wout,
                       unsigned short* __restrict__ W12, unsigned short* __restrict__ Wso,
                       unsigned short* __restrict__ Wo) {
    const int C12 = 8 * 768 * 1024 / 4, CSO = 8 * 1024 * 512 / 4, CWO = 8 * 1024 * 256 / 4;
    int c = blockIdx.x * 256 + threadIdx.x;
    float4 v; unsigned short* dst;
    if (c < C12) {
        int d = c * 4;
        int e = d / (768 * 1024);
        int rem = d - e * (768 * 1024);
        int r = rem >> 10, k = rem & 1023;
        const float* src = (r < 256) ? (Win + (((size_t)e * 256 + r) << 10) + k)
                                     : (Wsin + (((size_t)e * 512 + (r - 256)) << 10) + k);
        v = *(const float4*)src;
        dst = W12 + d;
    } else if (c < C12 + CSO) {
        int d = (c - C12) * 4;
        v = *(const float4*)(Wsout + d);
        dst = Wso + d;
    } else if (c < C12 + CSO + CWO) {
        int d = (c - C12 - CSO) * 4;
        v = *(const float4*)(Wout + d);
        dst = Wo + d;
    } else return;
    ushort4 o;
    o.x = f2bf(v.x); o.y = f2bf(v.y); o.z = f2bf(v.z); o.w = f2bf(v.w);
    *(ushort4*)dst = o;
}

// ---------------- K5: gather x into sorted bf16 rows + zero pads ----------------
__global__ void k_gather(const float* __restrict__ x, const int* __restrict__ perm,
                         unsigned short* __restrict__ Xs, unsigned short* __restrict__ SHb,
                         unsigned short* __restrict__ Yb) {
    int r = blockIdx.x, t = threadIdx.x;
    if (r < TOKS) {
        int tok = perm[r];
        float4 v = *(const float4*)(x + (size_t)tok * 1024 + t * 4);
        ushort4 o;
        o.x = f2bf(v.x); o.y = f2bf(v.y); o.z = f2bf(v.z); o.w = f2bf(v.w);
        *(ushort4*)(Xs + (size_t)r * 1024 + t * 4) = o;
    } else {
        ushort4 z = {0, 0, 0, 0};
        *(ushort4*)(Xs + (size_t)r * 1024 + t * 4) = z;
        if (t < 128) *(ushort4*)(SHb + (size_t)r * 512 + t * 4) = z;
        if (t < 64)  *(ushort4*)(Yb + (size_t)r * 256 + t * 4) = z;
    }
}

// ---------------- MFMA grouped GEMM, BM=128 BN=64 BK=32, 3-buf pipeline ----------------
// MODE 0: A=Xs (K=1024), B=W12 [e][768][1024]: col0<256 -> Ub fp16; else silu -> SHb
// MODE 1: A=SHb (K=512), B=Wso [e][1024][512]: region col0>>8 -> fp16 gates
// MODE 2: A=Yb (K=256),  B=Wo  [e][1024][256]: scatter fp32 out via perm
// 256 thr / 4 waves (2M x 2N; per-wave 64x32, acc[4][2]); per step 3 gl_lds
// per thread (2 A-pass + 1 B), vmcnt(3) steady; LDS 3x12KB = 36KB -> 4 blk/CU.
// K-step kt: [vmcnt(3): stage(kt) landed] [barrier] [issue stage(kt+2)]
// [ds_read buf kt%3 + 8 MFMA] [lgkmcnt(0)+sched_barrier].
template<int MODE, int KD>
__global__ __launch_bounds__(256, 4)
void k_mfma(const unsigned short* __restrict__ A, const unsigned short* __restrict__ Bw,
            const int* __restrict__ perm, const float* __restrict__ dparam,
            half_t* __restrict__ Ub, unsigned short* __restrict__ SHb,
            half_t* __restrict__ Aa, half_t* __restrict__ Wg,
            half_t* __restrict__ Cc, half_t* __restrict__ Sk,
            float* __restrict__ out,
            const int* __restrict__ tileE, const int* __restrict__ tileS,
            const int* __restrict__ tileR, const int* __restrict__ meta) {
    const int mt = blockIdx.x;
    if (mt >= meta[0]) return;
    const int e = tileE[mt], pos0 = tileS[mt], rows = tileR[mt];
    const int col0 = blockIdx.y * 64;
    const int tid = threadIdx.x;
    const int w = tid >> 6, lane = tid & 63, quad = lane >> 4, l15 = lane & 15;
    const int wm = w & 1, wn = w >> 1;          // 2M x 2N wave grid
    constexpr int NOUT = (MODE == 0) ? 768 : 1024;
    constexpr int NK = KD / 32;

    // triple-buffered: A [3][128][32], B [3][64][32] bf16 (12KB/buf set, 36KB)
    __shared__ unsigned short As[3][128 * 32];
    __shared__ unsigned short Bs[3][64 * 32];

    const int r0 = tid >> 2;                    // 0..63
    // pre-swizzled global chunk: chunk' = (tid&3) ^ ((row>>1)&3)
    const int c8s = ((tid & 3) ^ ((tid >> 3) & 3)) * 8;
    const unsigned short* ga = A + (size_t)(pos0 + r0) * KD + c8s;
    const unsigned short* gb = Bw + ((size_t)e * NOUT + col0 + r0) * KD + c8s;

    // fragment read offsets with matching XOR swizzle ((row>>1)&3 == (l15>>1)&3)
    const int sq = (quad ^ ((l15 >> 1) & 3)) * 8;
    int aoff[4], boff[2];
    #pragma unroll
    for (int i = 0; i < 4; i++) aoff[i] = (wm * 64 + i * 16 + l15) * 32 + sq;
    #pragma unroll
    for (int j = 0; j < 2; j++) boff[j] = (wn * 32 + j * 16 + l15) * 32 + sq;

    floatx4 acc[4][2] = {};

    // stage one BK=32 tile: A rows 0-63 and 64-127 (2 passes), B rows 0-63.
    // Wave w covers rows w*16..w*16+15 per pass; dest linear w*512 shorts.
    #define STAGE(buf, k0) do { \
        gl_lds16(ga + (k0),                    As[buf] + w * 512); \
        gl_lds16(ga + (size_t)64 * KD + (k0),  As[buf] + 2048 + w * 512); \
        gl_lds16(gb + (k0),                    Bs[buf] + w * 512); \
    } while (0)

    STAGE(0, 0);                      // 3 outstanding
    STAGE(1, 32);                     // 6 outstanding
    int cur = 0, pre = 2;
    for (int kt = 0; kt < NK; kt++) {
        if (kt < NK - 1) {
            asm volatile("s_waitcnt vmcnt(3)" ::: "memory");   // stage(kt) landed
        } else {
            asm volatile("s_waitcnt vmcnt(0)" ::: "memory");
        }
        __builtin_amdgcn_s_barrier();          // all waves' stage(kt) landed; prev reads drained
        asm volatile("" ::: "memory");
        if (kt + 2 < NK) STAGE(pre, (kt + 2) * 32);   // 2-deep prefetch, distinct buffer
        short8 af[4], bf[2];
        #pragma unroll
        for (int i = 0; i < 4; i++) af[i] = *(const short8*)(As[cur] + aoff[i]);
        #pragma unroll
        for (int j = 0; j < 2; j++) bf[j] = *(const short8*)(Bs[cur] + boff[j]);
        #pragma unroll
        for (int i = 0; i < 4; i++)
            #pragma unroll
            for (int j = 0; j < 2; j++)
                acc[i][j] = __builtin_amdgcn_mfma_f32_16x16x32_bf16(af[i], bf[j], acc[i][j], 0, 0, 0);
        asm volatile("s_waitcnt lgkmcnt(0)" ::: "memory");
        __builtin_amdgcn_sched_barrier(0);
        cur = (cur == 2) ? 0 : cur + 1;
        pre = (pre == 2) ? 0 : pre + 1;
    }
    #undef STAGE
    asm volatile("" ::: "memory");             // keep epilogue loads out of the loop

    // epilogue: per 16x16 tile, col = l15 (n), row = quad*4 + reg (m)
    #pragma unroll
    for (int i = 0; i < 4; i++) {
        #pragma unroll
        for (int r = 0; r < 4; r++) {
            int m = wm * 64 + i * 16 + quad * 4 + r;
            if (m >= rows) continue;
            size_t row = (size_t)(pos0 + m);
            if (MODE == 0) {
                if (col0 < 256) {
                    #pragma unroll
                    for (int j = 0; j < 2; j++) {
                        int n = col0 + wn * 32 + j * 16 + l15;
                        Ub[row * 256 + n] = (half_t)acc[i][j][r];
                    }
                } else {
                    #pragma unroll
                    for (int j = 0; j < 2; j++) {
                        int n = col0 - 256 + wn * 32 + j * 16 + l15;
                        float v = acc[i][j][r];
                        SHb[row * 512 + n] = f2bf(v * sigm(v));
                    }
                }
            } else if (MODE == 1) {
                int region = col0 >> 8;  // block-uniform
                #pragma unroll
                for (int j = 0; j < 2; j++) {
                    int n0 = (col0 & 255) + wn * 32 + j * 16 + l15;
                    size_t idx = row * 256 + (size_t)n0;
                    float v = acc[i][j][r];
                    if (region == 0) {
                        Aa[idx] = (half_t)sigm(v);
                    } else if (region == 1) {
                        Wg[idx] = (half_t)(ftanh(v) * (float)Ub[idx]);
                    } else if (region == 2) {
                        Cc[idx] = (half_t)ftanh(v);
                    } else {
                        Sk[idx] = (half_t)(dparam[e * 256 + n0] * sigm(v) * (float)Ub[idx]);
                    }
                }
            } else {
                int tok = perm[row];
                #pragma unroll
                for (int j = 0; j < 2; j++) {
                    int n = col0 + wn * 32 + j * 16 + l15;
                    out[(size_t)tok * 1024 + n] = acc[i][j][r];
                }
            }
        }
    }
}

// ---------------- K8a: chunk-local affine composition ----------------
__global__ void k_scanA(const half_t* __restrict__ Aa, const half_t* __restrict__ Wg,
                        const int* __restrict__ cStart, const int* __restrict__ cLen,
                        const int* __restrict__ meta,
                        float* __restrict__ SA, float* __restrict__ SQ) {
    int id = blockIdx.x;
    if (id >= meta[1]) return;
    int t = threadIdx.x;
    int s0 = cStart[id], L = cLen[id];
    size_t idx = (size_t)s0 * 256 + t;
    float p = 1.0f, q = 0.0f;
    for (int i = 0; i < L; i++) {
        float a = (float)Aa[idx], ww = (float)Wg[idx];
        q = a * q + ww;
        p *= a;
        idx += 256;
    }
    SA[(size_t)id * 256 + t] = p;
    SQ[(size_t)id * 256 + t] = q;
}

// ---------------- K8b: per-group serial combine -> chunk h_in ----------------
__global__ void k_scanB(const float* __restrict__ SA, const float* __restrict__ SQ,
                        const int* __restrict__ gBase, const int* __restrict__ cnt,
                        float* __restrict__ Hin) {
    int g = blockIdx.x, t = threadIdx.x;
    int base = gBase[g], nch = (cnt[g] + CHUNK - 1) / CHUNK;
    float h = 0.0f;
    for (int c = 0; c < nch; c++) {
        size_t k = (size_t)(base + c) * 256 + t;
        Hin[k] = h;
        h = SA[k] * h + SQ[k];
    }
}

// ---------------- K8c: re-scan with h_in, emit y (bf16) ----------------
__global__ void k_scanC(const half_t* __restrict__ Aa, const half_t* __restrict__ Wg,
                        const half_t* __restrict__ Cc, const half_t* __restrict__ Sk,
                        const int* __restrict__ cStart, const int* __restrict__ cLen,
                        const int* __restrict__ meta, const float* __restrict__ Hin,
                        unsigned short* __restrict__ Yb) {
    int id = blockIdx.x;
    if (id >= meta[1]) return;
    int t = threadIdx.x;
    int s0 = cStart[id], L = cLen[id];
    float h = Hin[(size_t)id * 256 + t];
    size_t idx = (size_t)s0 * 256 + t;
    for (int i = 0; i < L; i++) {
        float a = (float)Aa[idx], ww = (float)Wg[idx];
        float c = (float)Cc[idx], sk = (float)Sk[idx];
        h = a * h + ww;
        Yb[idx] = f2bf(c * h + sk);
        idx += 256;
    }
}

extern "C" void kernel_launch(void* const* d_in, const int* in_sizes, int n_in,
                              void* d_out, int out_size, void* d_ws, size_t ws_size,
                              hipStream_t stream) {
    const float* xin   = (const float*)d_in[0];
    const int*   tok   = (const int*)d_in[1];
    const float* Win   = (const float*)d_in[2];
    const float* Wsin  = (const float*)d_in[3];
    const float* Wsout = (const float*)d_in[4];
    const float* Wout  = (const float*)d_in[5];
    const float* dpar  = (const float*)d_in[6];
    float* out = (float*)d_out;

    size_t off = 0;
    char* base = (char*)d_ws;
    auto alloc = [&](size_t bytes) -> void* {
        void* p = base + off;
        off += (bytes + 255) & ~(size_t)255;
        return p;
    };
    half_t*         Ub  = (half_t*)alloc((size_t)RPAD * NN * 2);
    unsigned short* SHb = (unsigned short*)alloc((size_t)RPAD * HH * 2);
    unsigned short* Xs  = (unsigned short*)alloc((size_t)RPAD * DD * 2);
    unsigned short* Yb  = (unsigned short*)alloc((size_t)RPAD * NN * 2);
    half_t* Aa = (half_t*)alloc((size_t)TOKS * NN * 2);
    half_t* Wg = (half_t*)alloc((size_t)TOKS * NN * 2);
    half_t* Cc = (half_t*)alloc((size_t)TOKS * NN * 2);
    half_t* Sk = (half_t*)alloc((size_t)TOKS * NN * 2);
    unsigned short* W12 = (unsigned short*)alloc((size_t)8 * 768 * 1024 * 2);
    unsigned short* Wso = (unsigned short*)alloc((size_t)8 * 1024 * 512 * 2);
    unsigned short* Wo  = (unsigned short*)alloc((size_t)8 * 1024 * 256 * 2);
    float* SA  = (float*)alloc((size_t)MAXCHUNKS * 256 * 4);
    float* SQ  = (float*)alloc((size_t)MAXCHUNKS * 256 * 4);
    float* Hin = (float*)alloc((size_t)MAXCHUNKS * 256 * 4);
    int* perm   = (int*)alloc(TOKS * 4);
    int* cnt    = (int*)alloc(64 * 4);
    int* grpoff = (int*)alloc(64 * 4);
    int* tileE  = (int*)alloc(MAXTILES * 4);
    int* tileS  = (int*)alloc(MAXTILES * 4);
    int* tileR  = (int*)alloc(MAXTILES * 4);
    int* cGrp   = (int*)alloc(MAXCHUNKS * 4);
    int* cStart = (int*)alloc(MAXCHUNKS * 4);
    int* cLen   = (int*)alloc(MAXCHUNKS * 4);
    int* gBase  = (int*)alloc(64 * 4);
    int* meta   = (int*)alloc(16 * 4);

    k_route<<<8, 256, 0, stream>>>(tok, cnt);
    k_offsets<<<1, 256, 0, stream>>>(cnt, grpoff, tileE, tileS, tileR,
                                     cGrp, cStart, cLen, gBase, meta);
    k_scatter<<<8, 256, 0, stream>>>(tok, grpoff, perm);
    k_cvtw<<<12288, 256, 0, stream>>>(Win, Wsin, Wsout, Wout, W12, Wso, Wo);
    k_gather<<<RPAD, 256, 0, stream>>>(xin, perm, Xs, SHb, Yb);

    k_mfma<0, 1024><<<dim3(MAXTILES, 12), 256, 0, stream>>>(Xs, W12, perm, dpar,
        Ub, SHb, Aa, Wg, Cc, Sk, out, tileE, tileS, tileR, meta);
    k_mfma<1, 512><<<dim3(MAXTILES, 16), 256, 0, stream>>>(SHb, Wso, perm, dpar,
        Ub, SHb, Aa, Wg, Cc, Sk, out, tileE, tileS, tileR, meta);

    k_scanA<<<MAXCHUNKS, 256, 0, stream>>>(Aa, Wg, cStart, cLen, meta, SA, SQ);
    k_scanB<<<64, 256, 0, stream>>>(SA, SQ, gBase, cnt, Hin);
    k_scanC<<<MAXCHUNKS, 256, 0, stream>>>(Aa, Wg, Cc, Sk, cStart, cLen, meta, Hin, Yb);

    k_mfma<2, 256><<<dim3(MAXTILES, 16), 256, 0, stream>>>(Yb, Wo, perm, dpar,
        Ub, SHb, Aa, Wg, Cc, Sk, out, tileE, tileS, tileR, meta);
}

// Round 9
// 336.488 us; speedup vs baseline: 1.8415x; 1.0146x over previous
//
#include <hip/hip_runtime.h>

// HashRoutedSSMLayer: B=8,S=2048,D=1024,N=256,H=512,E=8 — fp32 in/out.
// Round 13: GEMM core = round-12 champion (BM=128 BN=64 BK=32, 3-buf 2-deep,
// 1 barrier/step, 4 blk/CU) + T5 setprio around MFMA (4 independent blocks/CU
// = phase-diverse regime). Aux overhaul: (1) k_scatter shfl-based packed
// prefix scan (24 shuffles vs 128 __syncthreads); (2) gates interleaved as
// AW=(a,w*u) / CS=(c,skip) half2-in-u32 -> scanA 1 load/iter, scanC 2 (was
// 2/4); (3) k_cvtw+k_gather fused into k_prep (one less launch).

#define TOKS 16384
#define RPAD 16512      // TOKS + 128 pad rows for tile overread
#define DD   1024
#define NN   256
#define HH   512
#define MAXTILES  136   // sum ceil(ce/128) <= 128+8
#define MAXCHUNKS 1088  // sum ceil(n_g/16) <= 1024+64
#define CHUNK 16
#define CVTBLKS 12288   // k_prep: first 12288 blocks convert weights

typedef short short8 __attribute__((ext_vector_type(8)));
typedef float floatx4 __attribute__((ext_vector_type(4)));
typedef _Float16 half_t;

#define AS_GLOBAL __attribute__((address_space(1)))
#define AS_LDS    __attribute__((address_space(3)))

__device__ __forceinline__ void gl_lds16(const void* g, void* l) {
    __builtin_amdgcn_global_load_lds((const AS_GLOBAL void*)g, (AS_LDS void*)l, 16, 0, 0);
}

__device__ __forceinline__ unsigned short f2bf(float f) {
    union { float f; unsigned u; } c; c.f = f;
    unsigned r = c.u + 0x7FFF + ((c.u >> 16) & 1);
    return (unsigned short)(r >> 16);
}
__device__ __forceinline__ int route_of(int token) {
    unsigned x = (unsigned)token;
    x ^= x >> 16; x *= 2246822507u; x ^= x >> 13; x *= 3266489909u; x ^= x >> 16;
    return (int)(x & 7u);
}
__device__ __forceinline__ float sigm(float v) { return 1.0f / (1.0f + __expf(-v)); }
__device__ __forceinline__ float ftanh(float v) {
    float e = __expf(2.0f * v);          // inf-safe: v>>0 -> 1, v<<0 -> -1
    return 1.0f - 2.0f / (e + 1.0f);
}

union H2 { unsigned u; half_t h[2]; };

// ---------------- K1: per-row route histogram ----------------
__global__ void k_route(const int* __restrict__ tok, int* __restrict__ cnt) {
    int b = blockIdx.x, tid = threadIdx.x;
    __shared__ int lc[256 * 8];
    #pragma unroll
    for (int e = 0; e < 8; e++) lc[tid * 8 + e] = 0;
    #pragma unroll
    for (int i = 0; i < 8; i++) {
        int e = route_of(tok[b * 2048 + tid * 8 + i]);
        lc[tid * 8 + e]++;
    }
    __syncthreads();
    if (tid < 8) {
        int s = 0;
        for (int t = 0; t < 256; t++) s += lc[t * 8 + tid];
        cnt[b * 8 + tid] = s;
    }
}

// ---------------- K2: offsets + tile table + chunk table ----------------
__global__ void k_offsets(const int* __restrict__ cnt, int* __restrict__ grpoff,
                          int* __restrict__ tileE, int* __restrict__ tileS,
                          int* __restrict__ tileR,
                          int* __restrict__ cGrp, int* __restrict__ cStart,
                          int* __restrict__ cLen, int* __restrict__ gBase,
                          int* __restrict__ meta) {
    __shared__ int sc[64], ce[8], eoff[9], etile[9], gb[65], go[64];
    int tid = threadIdx.x;
    if (tid < 64) sc[tid] = cnt[tid];
    __syncthreads();
    if (tid < 8) { int s = 0; for (int b = 0; b < 8; b++) s += sc[b * 8 + tid]; ce[tid] = s; }
    __syncthreads();
    if (tid == 0) {
        eoff[0] = 0; etile[0] = 0;
        for (int e = 0; e < 8; e++) {
            eoff[e + 1] = eoff[e] + ce[e];
            etile[e + 1] = etile[e] + (ce[e] + 127) / 128;
        }
        meta[0] = etile[8];
        gb[0] = 0;
        for (int g = 0; g < 64; g++) gb[g + 1] = gb[g] + (sc[g] + CHUNK - 1) / CHUNK;
        meta[1] = gb[64];
    }
    __syncthreads();
    if (tid < 64) {
        int b = tid >> 3, e = tid & 7;
        int run = eoff[e];
        for (int b2 = 0; b2 < b; b2++) run += sc[b2 * 8 + e];
        go[tid] = run;
        grpoff[tid] = run;
    }
    __syncthreads();
    if (tid < 8) {   // tiles for expert tid
        int e = tid, st = eoff[e], c = ce[e], t0 = etile[e];
        for (int i = 0, k = 0; i < c; i += 128, k++) {
            tileE[t0 + k] = e; tileS[t0 + k] = st + i;
            tileR[t0 + k] = (c - i < 128) ? (c - i) : 128;
        }
    }
    if (tid < 64) {  // chunks for group tid
        int g = tid, n = sc[g], base = gb[g], s0 = go[g];
        gBase[g] = base;
        for (int i = 0, c = 0; i < n; i += CHUNK, c++) {
            cGrp[base + c] = g;
            cStart[base + c] = s0 + i;
            cLen[base + c] = (n - i < CHUNK) ? (n - i) : CHUNK;
        }
    }
}

// ---------------- K3: stable counting-sort scatter (shfl-scan) ----------------
// Exclusive prefix over tid of per-thread expert counts, via 4 packed u32
// (2 experts x 16-bit fields each; totals <= 2048 so no field overflow).
// Order identical to the old 128-barrier version: prefix in tid order,
// in-thread increments in token (time) order — scan stability preserved.
__global__ void k_scatter(const int* __restrict__ tok, const int* __restrict__ grpoff,
                          int* __restrict__ perm) {
    int b = blockIdx.x, tid = threadIdx.x;
    int lane = tid & 63, w = tid >> 6;
    __shared__ unsigned wsum[4][4];
    int r[8];
    int myc[8] = {0,0,0,0,0,0,0,0};
    #pragma unroll
    for (int i = 0; i < 8; i++) {
        int e = route_of(tok[b * 2048 + tid * 8 + i]);
        r[i] = e; myc[e]++;
    }
    unsigned p[4], v[4];
    #pragma unroll
    for (int k = 0; k < 4; k++) {
        p[k] = (unsigned)myc[2 * k] | ((unsigned)myc[2 * k + 1] << 16);
        v[k] = p[k];
    }
    #pragma unroll
    for (int off = 1; off < 64; off <<= 1) {
        #pragma unroll
        for (int k = 0; k < 4; k++) {
            unsigned o = __shfl_up(v[k], off, 64);
            if (lane >= off) v[k] += o;
        }
    }
    if (lane == 63) {
        #pragma unroll
        for (int k = 0; k < 4; k++) wsum[w][k] = v[k];
    }
    __syncthreads();
    unsigned add[4] = {0, 0, 0, 0};
    for (int ww = 0; ww < w; ww++)
        #pragma unroll
        for (int k = 0; k < 4; k++) add[k] += wsum[ww][k];
    int basep[8];
    #pragma unroll
    for (int e = 0; e < 8; e++) {
        unsigned ex = v[e >> 1] + add[e >> 1] - p[e >> 1];   // exclusive prefix
        basep[e] = grpoff[b * 8 + e] + (int)((e & 1) ? (ex >> 16) : (ex & 0xffffu));
    }
    #pragma unroll
    for (int i = 0; i < 8; i++) {
        int e = r[i];
        perm[basep[e]++] = b * 2048 + tid * 8 + i;
    }
}

// ---------------- K4+K5 fused: weight cvt + gather x ----------------
__global__ void k_prep(const float* __restrict__ Win, const float* __restrict__ Wsin,
                       const float* __restrict__ Wsout, const float* __restrict__ Wout,
                       unsigned short* __restrict__ W12, unsigned short* __restrict__ Wso,
                       unsigned short* __restrict__ Wo,
                       const float* __restrict__ x, const int* __restrict__ perm,
                       unsigned short* __restrict__ Xs, unsigned short* __restrict__ SHb,
                       unsigned short* __restrict__ Yb) {
    int blk = blockIdx.x, tid = threadIdx.x;
    if (blk < CVTBLKS) {
        const int C12 = 8 * 768 * 1024 / 4, CSO = 8 * 1024 * 512 / 4, CWO = 8 * 1024 * 256 / 4;
        int c = blk * 256 + tid;
        float4 v; unsigned short* dst;
        if (c < C12) {
            int d = c * 4;
            int e = d / (768 * 1024);
            int rem = d - e * (768 * 1024);
            int r = rem >> 10, k = rem & 1023;
            const float* src = (r < 256) ? (Win + (((size_t)e * 256 + r) << 10) + k)
                                         : (Wsin + (((size_t)e * 512 + (r - 256)) << 10) + k);
            v = *(const float4*)src;
            dst = W12 + d;
        } else if (c < C12 + CSO) {
            int d = (c - C12) * 4;
            v = *(const float4*)(Wsout + d);
            dst = Wso + d;
        } else {
            int d = (c - C12 - CSO) * 4;
            v = *(const float4*)(Wout + d);
            dst = Wo + d;
        }
        ushort4 o;
        o.x = f2bf(v.x); o.y = f2bf(v.y); o.z = f2bf(v.z); o.w = f2bf(v.w);
        *(ushort4*)dst = o;
    } else {
        int r = blk - CVTBLKS;
        if (r < TOKS) {
            int tok = perm[r];
            float4 v = *(const float4*)(x + (size_t)tok * 1024 + tid * 4);
            ushort4 o;
            o.x = f2bf(v.x); o.y = f2bf(v.y); o.z = f2bf(v.z); o.w = f2bf(v.w);
            *(ushort4*)(Xs + (size_t)r * 1024 + tid * 4) = o;
        } else {
            ushort4 z = {0, 0, 0, 0};
            *(ushort4*)(Xs + (size_t)r * 1024 + tid * 4) = z;
            if (tid < 128) *(ushort4*)(SHb + (size_t)r * 512 + tid * 4) = z;
            if (tid < 64)  *(ushort4*)(Yb + (size_t)r * 256 + tid * 4) = z;
        }
    }
}

// ---------------- MFMA grouped GEMM, BM=128 BN=64 BK=32, 3-buf pipeline ----------------
// MODE 0: A=Xs (K=1024), B=W12: col0<256 -> Ub fp16; else silu -> SHb bf16
// MODE 1: A=SHb (K=512), B=Wso: region col0>>8 -> interleaved AW/CS half pairs
// MODE 2: A=Yb (K=256),  B=Wo : scatter fp32 out via perm
// 256 thr / 4 waves (2M x 2N; per-wave 64x32, acc[4][2]); 3 gl_lds/thread/step,
// vmcnt(3) steady; LDS 36KB -> 4 blk/CU. T5 setprio around the MFMA cluster
// (4 independent blocks/CU = phase-diverse regime, m191-positive case).
template<int MODE, int KD>
__global__ __launch_bounds__(256, 4)
void k_mfma(const unsigned short* __restrict__ A, const unsigned short* __restrict__ Bw,
            const int* __restrict__ perm, const float* __restrict__ dparam,
            half_t* __restrict__ Ub, unsigned short* __restrict__ SHb,
            half_t* __restrict__ AW, half_t* __restrict__ CS,
            float* __restrict__ out,
            const int* __restrict__ tileE, const int* __restrict__ tileS,
            const int* __restrict__ tileR, const int* __restrict__ meta) {
    const int mt = blockIdx.x;
    if (mt >= meta[0]) return;
    const int e = tileE[mt], pos0 = tileS[mt], rows = tileR[mt];
    const int col0 = blockIdx.y * 64;
    const int tid = threadIdx.x;
    const int w = tid >> 6, lane = tid & 63, quad = lane >> 4, l15 = lane & 15;
    const int wm = w & 1, wn = w >> 1;          // 2M x 2N wave grid
    constexpr int NOUT = (MODE == 0) ? 768 : 1024;
    constexpr int NK = KD / 32;

    // triple-buffered: A [3][128][32], B [3][64][32] bf16 (12KB/buf set, 36KB)
    __shared__ unsigned short As[3][128 * 32];
    __shared__ unsigned short Bs[3][64 * 32];

    const int r0 = tid >> 2;                    // 0..63
    // pre-swizzled global chunk: chunk' = (tid&3) ^ ((row>>1)&3)
    const int c8s = ((tid & 3) ^ ((tid >> 3) & 3)) * 8;
    const unsigned short* ga = A + (size_t)(pos0 + r0) * KD + c8s;
    const unsigned short* gb = Bw + ((size_t)e * NOUT + col0 + r0) * KD + c8s;

    // fragment read offsets with matching XOR swizzle ((row>>1)&3 == (l15>>1)&3)
    const int sq = (quad ^ ((l15 >> 1) & 3)) * 8;
    int aoff[4], boff[2];
    #pragma unroll
    for (int i = 0; i < 4; i++) aoff[i] = (wm * 64 + i * 16 + l15) * 32 + sq;
    #pragma unroll
    for (int j = 0; j < 2; j++) boff[j] = (wn * 32 + j * 16 + l15) * 32 + sq;

    floatx4 acc[4][2] = {};

    // stage one BK=32 tile: A rows 0-63 and 64-127 (2 passes), B rows 0-63.
    #define STAGE(buf, k0) do { \
        gl_lds16(ga + (k0),                    As[buf] + w * 512); \
        gl_lds16(ga + (size_t)64 * KD + (k0),  As[buf] + 2048 + w * 512); \
        gl_lds16(gb + (k0),                    Bs[buf] + w * 512); \
    } while (0)

    STAGE(0, 0);                      // 3 outstanding
    STAGE(1, 32);                     // 6 outstanding
    int cur = 0, pre = 2;
    for (int kt = 0; kt < NK; kt++) {
        if (kt < NK - 1) {
            asm volatile("s_waitcnt vmcnt(3)" ::: "memory");   // stage(kt) landed
        } else {
            asm volatile("s_waitcnt vmcnt(0)" ::: "memory");
        }
        __builtin_amdgcn_s_barrier();          // all waves' stage(kt) landed; prev reads drained
        asm volatile("" ::: "memory");
        if (kt + 2 < NK) STAGE(pre, (kt + 2) * 32);   // 2-deep prefetch, distinct buffer
        short8 af[4], bf[2];
        #pragma unroll
        for (int i = 0; i < 4; i++) af[i] = *(const short8*)(As[cur] + aoff[i]);
        #pragma unroll
        for (int j = 0; j < 2; j++) bf[j] = *(const short8*)(Bs[cur] + boff[j]);
        __builtin_amdgcn_s_setprio(1);
        #pragma unroll
        for (int i = 0; i < 4; i++)
            #pragma unroll
            for (int j = 0; j < 2; j++)
                acc[i][j] = __builtin_amdgcn_mfma_f32_16x16x32_bf16(af[i], bf[j], acc[i][j], 0, 0, 0);
        __builtin_amdgcn_s_setprio(0);
        asm volatile("s_waitcnt lgkmcnt(0)" ::: "memory");
        __builtin_amdgcn_sched_barrier(0);
        cur = (cur == 2) ? 0 : cur + 1;
        pre = (pre == 2) ? 0 : pre + 1;
    }
    #undef STAGE
    asm volatile("" ::: "memory");             // keep epilogue loads out of the loop

    // epilogue: per 16x16 tile, col = l15 (n), row = quad*4 + reg (m)
    #pragma unroll
    for (int i = 0; i < 4; i++) {
        #pragma unroll
        for (int r = 0; r < 4; r++) {
            int m = wm * 64 + i * 16 + quad * 4 + r;
            if (m >= rows) continue;
            size_t row = (size_t)(pos0 + m);
            if (MODE == 0) {
                if (col0 < 256) {
                    #pragma unroll
                    for (int j = 0; j < 2; j++) {
                        int n = col0 + wn * 32 + j * 16 + l15;
                        Ub[row * 256 + n] = (half_t)acc[i][j][r];
                    }
                } else {
                    #pragma unroll
                    for (int j = 0; j < 2; j++) {
                        int n = col0 - 256 + wn * 32 + j * 16 + l15;
                        float v = acc[i][j][r];
                        SHb[row * 512 + n] = f2bf(v * sigm(v));
                    }
                }
            } else if (MODE == 1) {
                int region = col0 >> 8;  // block-uniform
                #pragma unroll
                for (int j = 0; j < 2; j++) {
                    int n0 = (col0 & 255) + wn * 32 + j * 16 + l15;
                    float v = acc[i][j][r];
                    size_t rb = row * 512 + (size_t)n0 * 2;   // interleaved pair slot
                    if (region == 0) {
                        AW[rb] = (half_t)sigm(v);
                    } else if (region == 1) {
                        AW[rb + 1] = (half_t)(ftanh(v) * (float)Ub[row * 256 + n0]);
                    } else if (region == 2) {
                        CS[rb] = (half_t)ftanh(v);
                    } else {
                        CS[rb + 1] = (half_t)(dparam[e * 256 + n0] * sigm(v) * (float)Ub[row * 256 + n0]);
                    }
                }
            } else {
                int tok = perm[row];
                #pragma unroll
                for (int j = 0; j < 2; j++) {
                    int n = col0 + wn * 32 + j * 16 + l15;
                    out[(size_t)tok * 1024 + n] = acc[i][j][r];
                }
            }
        }
    }
}

// ---------------- K8a: chunk-local affine composition (interleaved AW) ----------------
__global__ void k_scanA(const half_t* __restrict__ AW,
                        const int* __restrict__ cStart, const int* __restrict__ cLen,
                        const int* __restrict__ meta,
                        float* __restrict__ SA, float* __restrict__ SQ) {
    int id = blockIdx.x;
    if (id >= meta[1]) return;
    int t = threadIdx.x;
    int s0 = cStart[id], L = cLen[id];
    const unsigned* AW32 = (const unsigned*)AW;
    size_t idx = (size_t)s0 * 256 + t;          // u32-word index == token*256+n
    float p = 1.0f, q = 0.0f;
    for (int i = 0; i < L; i++) {
        H2 cv; cv.u = AW32[idx];
        float a = (float)cv.h[0], ww = (float)cv.h[1];
        q = a * q + ww;
        p *= a;
        idx += 256;
    }
    SA[(size_t)id * 256 + t] = p;
    SQ[(size_t)id * 256 + t] = q;
}

// ---------------- K8b: per-group serial combine -> chunk h_in ----------------
__global__ void k_scanB(const float* __restrict__ SA, const float* __restrict__ SQ,
                        const int* __restrict__ gBase, const int* __restrict__ cnt,
                        float* __restrict__ Hin) {
    int g = blockIdx.x, t = threadIdx.x;
    int base = gBase[g], nch = (cnt[g] + CHUNK - 1) / CHUNK;
    float h = 0.0f;
    for (int c = 0; c < nch; c++) {
        size_t k = (size_t)(base + c) * 256 + t;
        Hin[k] = h;
        h = SA[k] * h + SQ[k];
    }
}

// ---------------- K8c: re-scan with h_in, emit y (bf16) ----------------
__global__ void k_scanC(const half_t* __restrict__ AW, const half_t* __restrict__ CS,
                        const int* __restrict__ cStart, const int* __restrict__ cLen,
                        const int* __restrict__ meta, const float* __restrict__ Hin,
                        unsigned short* __restrict__ Yb) {
    int id = blockIdx.x;
    if (id >= meta[1]) return;
    int t = threadIdx.x;
    int s0 = cStart[id], L = cLen[id];
    const unsigned* AW32 = (const unsigned*)AW;
    const unsigned* CS32 = (const unsigned*)CS;
    float h = Hin[(size_t)id * 256 + t];
    size_t idx = (size_t)s0 * 256 + t;          // u32 index for AW/CS, u16 for Yb
    for (int i = 0; i < L; i++) {
        H2 av; av.u = AW32[idx];
        H2 cv; cv.u = CS32[idx];
        float a = (float)av.h[0], ww = (float)av.h[1];
        float c = (float)cv.h[0], sk = (float)cv.h[1];
        h = a * h + ww;
        Yb[idx] = f2bf(c * h + sk);
        idx += 256;
    }
}

extern "C" void kernel_launch(void* const* d_in, const int* in_sizes, int n_in,
                              void* d_out, int out_size, void* d_ws, size_t ws_size,
                              hipStream_t stream) {
    const float* xin   = (const float*)d_in[0];
    const int*   tok   = (const int*)d_in[1];
    const float* Win   = (const float*)d_in[2];
    const float* Wsin  = (const float*)d_in[3];
    const float* Wsout = (const float*)d_in[4];
    const float* Wout  = (const float*)d_in[5];
    const float* dpar  = (const float*)d_in[6];
    float* out = (float*)d_out;

    size_t off = 0;
    char* base = (char*)d_ws;
    auto alloc = [&](size_t bytes) -> void* {
        void* p = base + off;
        off += (bytes + 255) & ~(size_t)255;
        return p;
    };
    half_t*         Ub  = (half_t*)alloc((size_t)RPAD * NN * 2);
    unsigned short* SHb = (unsigned short*)alloc((size_t)RPAD * HH * 2);
    unsigned short* Xs  = (unsigned short*)alloc((size_t)RPAD * DD * 2);
    unsigned short* Yb  = (unsigned short*)alloc((size_t)RPAD * NN * 2);
    half_t* AW = (half_t*)alloc((size_t)TOKS * NN * 4);   // (a, w*u) pairs
    half_t* CS = (half_t*)alloc((size_t)TOKS * NN * 4);   // (c, skip) pairs
    unsigned short* W12 = (unsigned short*)alloc((size_t)8 * 768 * 1024 * 2);
    unsigned short* Wso = (unsigned short*)alloc((size_t)8 * 1024 * 512 * 2);
    unsigned short* Wo  = (unsigned short*)alloc((size_t)8 * 1024 * 256 * 2);
    float* SA  = (float*)alloc((size_t)MAXCHUNKS * 256 * 4);
    float* SQ  = (float*)alloc((size_t)MAXCHUNKS * 256 * 4);
    float* Hin = (float*)alloc((size_t)MAXCHUNKS * 256 * 4);
    int* perm   = (int*)alloc(TOKS * 4);
    int* cnt    = (int*)alloc(64 * 4);
    int* grpoff = (int*)alloc(64 * 4);
    int* tileE  = (int*)alloc(MAXTILES * 4);
    int* tileS  = (int*)alloc(MAXTILES * 4);
    int* tileR  = (int*)alloc(MAXTILES * 4);
    int* cGrp   = (int*)alloc(MAXCHUNKS * 4);
    int* cStart = (int*)alloc(MAXCHUNKS * 4);
    int* cLen   = (int*)alloc(MAXCHUNKS * 4);
    int* gBase  = (int*)alloc(64 * 4);
    int* meta   = (int*)alloc(16 * 4);

    k_route<<<8, 256, 0, stream>>>(tok, cnt);
    k_offsets<<<1, 256, 0, stream>>>(cnt, grpoff, tileE, tileS, tileR,
                                     cGrp, cStart, cLen, gBase, meta);
    k_scatter<<<8, 256, 0, stream>>>(tok, grpoff, perm);
    k_prep<<<CVTBLKS + RPAD, 256, 0, stream>>>(Win, Wsin, Wsout, Wout, W12, Wso, Wo,
                                               xin, perm, Xs, SHb, Yb);

    k_mfma<0, 1024><<<dim3(MAXTILES, 12), 256, 0, stream>>>(Xs, W12, perm, dpar,
        Ub, SHb, AW, CS, out, tileE, tileS, tileR, meta);
    k_mfma<1, 512><<<dim3(MAXTILES, 16), 256, 0, stream>>>(SHb, Wso, perm, dpar,
        Ub, SHb, AW, CS, out, tileE, tileS, tileR, meta);

    k_scanA<<<MAXCHUNKS, 256, 0, stream>>>(AW, cStart, cLen, meta, SA, SQ);
    k_scanB<<<64, 256, 0, stream>>>(SA, SQ, gBase, cnt, Hin);
    k_scanC<<<MAXCHUNKS, 256, 0, stream>>>(AW, CS, cStart, cLen, meta, Hin, Yb);

    k_mfma<2, 256><<<dim3(MAXTILES, 16), 256, 0, stream>>>(Yb, Wo, perm, dpar,
        Ub, SHb, AW, CS, out, tileE, tileS, tileR, meta);
}

// Round 10
// 336.213 us; speedup vs baseline: 1.8430x; 1.0008x over previous
//
#include <hip/hip_runtime.h>

// HashRoutedSSMLayer: B=8,S=2048,D=1024,N=256,H=512,E=8 — fp32 in/out.
// Round 14: revert round-13's interleaved AW/CS gate layout — cross-block
// half-word writes doubled mode-1 HBM WRITE (32->63MB, +2.4us). Back to 4
// separate coalesced gate buffers (round-12). Keep: shfl k_scatter, fused
// k_prep, T5 setprio, BM=128 BN=64 BK=32 3-buf 4blk/CU GEMM core.
// New: CHUNK 16->32 (scanB serial combine 17->9 iters; scanA/C 1088->576 blocks).

#define TOKS 16384
#define RPAD 16512      // TOKS + 128 pad rows for tile overread
#define DD   1024
#define NN   256
#define HH   512
#define MAXTILES  136   // sum ceil(ce/128) <= 128+8
#define MAXCHUNKS 576   // sum ceil(n_g/32) <= 512+64
#define CHUNK 32
#define CVTBLKS 12288   // k_prep: first 12288 blocks convert weights

typedef short short8 __attribute__((ext_vector_type(8)));
typedef float floatx4 __attribute__((ext_vector_type(4)));
typedef _Float16 half_t;

#define AS_GLOBAL __attribute__((address_space(1)))
#define AS_LDS    __attribute__((address_space(3)))

__device__ __forceinline__ void gl_lds16(const void* g, void* l) {
    __builtin_amdgcn_global_load_lds((const AS_GLOBAL void*)g, (AS_LDS void*)l, 16, 0, 0);
}

__device__ __forceinline__ unsigned short f2bf(float f) {
    union { float f; unsigned u; } c; c.f = f;
    unsigned r = c.u + 0x7FFF + ((c.u >> 16) & 1);
    return (unsigned short)(r >> 16);
}
__device__ __forceinline__ int route_of(int token) {
    unsigned x = (unsigned)token;
    x ^= x >> 16; x *= 2246822507u; x ^= x >> 13; x *= 3266489909u; x ^= x >> 16;
    return (int)(x & 7u);
}
__device__ __forceinline__ float sigm(float v) { return 1.0f / (1.0f + __expf(-v)); }
__device__ __forceinline__ float ftanh(float v) {
    float e = __expf(2.0f * v);          // inf-safe: v>>0 -> 1, v<<0 -> -1
    return 1.0f - 2.0f / (e + 1.0f);
}

// ---------------- K1: per-row route histogram ----------------
__global__ void k_route(const int* __restrict__ tok, int* __restrict__ cnt) {
    int b = blockIdx.x, tid = threadIdx.x;
    __shared__ int lc[256 * 8];
    #pragma unroll
    for (int e = 0; e < 8; e++) lc[tid * 8 + e] = 0;
    #pragma unroll
    for (int i = 0; i < 8; i++) {
        int e = route_of(tok[b * 2048 + tid * 8 + i]);
        lc[tid * 8 + e]++;
    }
    __syncthreads();
    if (tid < 8) {
        int s = 0;
        for (int t = 0; t < 256; t++) s += lc[t * 8 + tid];
        cnt[b * 8 + tid] = s;
    }
}

// ---------------- K2: offsets + tile table + chunk table ----------------
__global__ void k_offsets(const int* __restrict__ cnt, int* __restrict__ grpoff,
                          int* __restrict__ tileE, int* __restrict__ tileS,
                          int* __restrict__ tileR,
                          int* __restrict__ cGrp, int* __restrict__ cStart,
                          int* __restrict__ cLen, int* __restrict__ gBase,
                          int* __restrict__ meta) {
    __shared__ int sc[64], ce[8], eoff[9], etile[9], gb[65], go[64];
    int tid = threadIdx.x;
    if (tid < 64) sc[tid] = cnt[tid];
    __syncthreads();
    if (tid < 8) { int s = 0; for (int b = 0; b < 8; b++) s += sc[b * 8 + tid]; ce[tid] = s; }
    __syncthreads();
    if (tid == 0) {
        eoff[0] = 0; etile[0] = 0;
        for (int e = 0; e < 8; e++) {
            eoff[e + 1] = eoff[e] + ce[e];
            etile[e + 1] = etile[e] + (ce[e] + 127) / 128;
        }
        meta[0] = etile[8];
        gb[0] = 0;
        for (int g = 0; g < 64; g++) gb[g + 1] = gb[g] + (sc[g] + CHUNK - 1) / CHUNK;
        meta[1] = gb[64];
    }
    __syncthreads();
    if (tid < 64) {
        int b = tid >> 3, e = tid & 7;
        int run = eoff[e];
        for (int b2 = 0; b2 < b; b2++) run += sc[b2 * 8 + e];
        go[tid] = run;
        grpoff[tid] = run;
    }
    __syncthreads();
    if (tid < 8) {   // tiles for expert tid
        int e = tid, st = eoff[e], c = ce[e], t0 = etile[e];
        for (int i = 0, k = 0; i < c; i += 128, k++) {
            tileE[t0 + k] = e; tileS[t0 + k] = st + i;
            tileR[t0 + k] = (c - i < 128) ? (c - i) : 128;
        }
    }
    if (tid < 64) {  // chunks for group tid
        int g = tid, n = sc[g], base = gb[g], s0 = go[g];
        gBase[g] = base;
        for (int i = 0, c = 0; i < n; i += CHUNK, c++) {
            cGrp[base + c] = g;
            cStart[base + c] = s0 + i;
            cLen[base + c] = (n - i < CHUNK) ? (n - i) : CHUNK;
        }
    }
}

// ---------------- K3: stable counting-sort scatter (shfl-scan) ----------------
__global__ void k_scatter(const int* __restrict__ tok, const int* __restrict__ grpoff,
                          int* __restrict__ perm) {
    int b = blockIdx.x, tid = threadIdx.x;
    int lane = tid & 63, w = tid >> 6;
    __shared__ unsigned wsum[4][4];
    int r[8];
    int myc[8] = {0,0,0,0,0,0,0,0};
    #pragma unroll
    for (int i = 0; i < 8; i++) {
        int e = route_of(tok[b * 2048 + tid * 8 + i]);
        r[i] = e; myc[e]++;
    }
    unsigned p[4], v[4];
    #pragma unroll
    for (int k = 0; k < 4; k++) {
        p[k] = (unsigned)myc[2 * k] | ((unsigned)myc[2 * k + 1] << 16);
        v[k] = p[k];
    }
    #pragma unroll
    for (int off = 1; off < 64; off <<= 1) {
        #pragma unroll
        for (int k = 0; k < 4; k++) {
            unsigned o = __shfl_up(v[k], off, 64);
            if (lane >= off) v[k] += o;
        }
    }
    if (lane == 63) {
        #pragma unroll
        for (int k = 0; k < 4; k++) wsum[w][k] = v[k];
    }
    __syncthreads();
    unsigned add[4] = {0, 0, 0, 0};
    for (int ww = 0; ww < w; ww++)
        #pragma unroll
        for (int k = 0; k < 4; k++) add[k] += wsum[ww][k];
    int basep[8];
    #pragma unroll
    for (int e = 0; e < 8; e++) {
        unsigned ex = v[e >> 1] + add[e >> 1] - p[e >> 1];   // exclusive prefix
        basep[e] = grpoff[b * 8 + e] + (int)((e & 1) ? (ex >> 16) : (ex & 0xffffu));
    }
    #pragma unroll
    for (int i = 0; i < 8; i++) {
        int e = r[i];
        perm[basep[e]++] = b * 2048 + tid * 8 + i;
    }
}

// ---------------- K4+K5 fused: weight cvt + gather x ----------------
__global__ void k_prep(const float* __restrict__ Win, const float* __restrict__ Wsin,
                       const float* __restrict__ Wsout, const float* __restrict__ Wout,
                       unsigned short* __restrict__ W12, unsigned short* __restrict__ Wso,
                       unsigned short* __restrict__ Wo,
                       const float* __restrict__ x, const int* __restrict__ perm,
                       unsigned short* __restrict__ Xs, unsigned short* __restrict__ SHb,
                       unsigned short* __restrict__ Yb) {
    int blk = blockIdx.x, tid = threadIdx.x;
    if (blk < CVTBLKS) {
        const int C12 = 8 * 768 * 1024 / 4, CSO = 8 * 1024 * 512 / 4;
        int c = blk * 256 + tid;
        float4 v; unsigned short* dst;
        if (c < C12) {
            int d = c * 4;
            int e = d / (768 * 1024);
            int rem = d - e * (768 * 1024);
            int r = rem >> 10, k = rem & 1023;
            const float* src = (r < 256) ? (Win + (((size_t)e * 256 + r) << 10) + k)
                                         : (Wsin + (((size_t)e * 512 + (r - 256)) << 10) + k);
            v = *(const float4*)src;
            dst = W12 + d;
        } else if (c < C12 + CSO) {
            int d = (c - C12) * 4;
            v = *(const float4*)(Wsout + d);
            dst = Wso + d;
        } else {
            int d = (c - C12 - CSO) * 4;
            v = *(const float4*)(Wout + d);
            dst = Wo + d;
        }
        ushort4 o;
        o.x = f2bf(v.x); o.y = f2bf(v.y); o.z = f2bf(v.z); o.w = f2bf(v.w);
        *(ushort4*)dst = o;
    } else {
        int r = blk - CVTBLKS;
        if (r < TOKS) {
            int tok = perm[r];
            float4 v = *(const float4*)(x + (size_t)tok * 1024 + tid * 4);
            ushort4 o;
            o.x = f2bf(v.x); o.y = f2bf(v.y); o.z = f2bf(v.z); o.w = f2bf(v.w);
            *(ushort4*)(Xs + (size_t)r * 1024 + tid * 4) = o;
        } else {
            ushort4 z = {0, 0, 0, 0};
            *(ushort4*)(Xs + (size_t)r * 1024 + tid * 4) = z;
            if (tid < 128) *(ushort4*)(SHb + (size_t)r * 512 + tid * 4) = z;
            if (tid < 64)  *(ushort4*)(Yb + (size_t)r * 256 + tid * 4) = z;
        }
    }
}

// ---------------- MFMA grouped GEMM, BM=128 BN=64 BK=32, 3-buf pipeline ----------------
// MODE 0: A=Xs (K=1024), B=W12: col0<256 -> Ub fp16; else silu -> SHb bf16
// MODE 1: A=SHb (K=512), B=Wso: region col0>>8 -> fp16 gates (separate bufs)
// MODE 2: A=Yb (K=256),  B=Wo : scatter fp32 out via perm
// 256 thr / 4 waves (2M x 2N; per-wave 64x32, acc[4][2]); 3 gl_lds/thread/step,
// vmcnt(3) steady; LDS 36KB -> 4 blk/CU; T5 setprio around MFMA cluster.
template<int MODE, int KD>
__global__ __launch_bounds__(256, 4)
void k_mfma(const unsigned short* __restrict__ A, const unsigned short* __restrict__ Bw,
            const int* __restrict__ perm, const float* __restrict__ dparam,
            half_t* __restrict__ Ub, unsigned short* __restrict__ SHb,
            half_t* __restrict__ Aa, half_t* __restrict__ Wg,
            half_t* __restrict__ Cc, half_t* __restrict__ Sk,
            float* __restrict__ out,
            const int* __restrict__ tileE, const int* __restrict__ tileS,
            const int* __restrict__ tileR, const int* __restrict__ meta) {
    const int mt = blockIdx.x;
    if (mt >= meta[0]) return;
    const int e = tileE[mt], pos0 = tileS[mt], rows = tileR[mt];
    const int col0 = blockIdx.y * 64;
    const int tid = threadIdx.x;
    const int w = tid >> 6, lane = tid & 63, quad = lane >> 4, l15 = lane & 15;
    const int wm = w & 1, wn = w >> 1;          // 2M x 2N wave grid
    constexpr int NOUT = (MODE == 0) ? 768 : 1024;
    constexpr int NK = KD / 32;

    // triple-buffered: A [3][128][32], B [3][64][32] bf16 (12KB/buf set, 36KB)
    __shared__ unsigned short As[3][128 * 32];
    __shared__ unsigned short Bs[3][64 * 32];

    const int r0 = tid >> 2;                    // 0..63
    // pre-swizzled global chunk: chunk' = (tid&3) ^ ((row>>1)&3)
    const int c8s = ((tid & 3) ^ ((tid >> 3) & 3)) * 8;
    const unsigned short* ga = A + (size_t)(pos0 + r0) * KD + c8s;
    const unsigned short* gb = Bw + ((size_t)e * NOUT + col0 + r0) * KD + c8s;

    // fragment read offsets with matching XOR swizzle ((row>>1)&3 == (l15>>1)&3)
    const int sq = (quad ^ ((l15 >> 1) & 3)) * 8;
    int aoff[4], boff[2];
    #pragma unroll
    for (int i = 0; i < 4; i++) aoff[i] = (wm * 64 + i * 16 + l15) * 32 + sq;
    #pragma unroll
    for (int j = 0; j < 2; j++) boff[j] = (wn * 32 + j * 16 + l15) * 32 + sq;

    floatx4 acc[4][2] = {};

    // stage one BK=32 tile: A rows 0-63 and 64-127 (2 passes), B rows 0-63.
    #define STAGE(buf, k0) do { \
        gl_lds16(ga + (k0),                    As[buf] + w * 512); \
        gl_lds16(ga + (size_t)64 * KD + (k0),  As[buf] + 2048 + w * 512); \
        gl_lds16(gb + (k0),                    Bs[buf] + w * 512); \
    } while (0)

    STAGE(0, 0);                      // 3 outstanding
    STAGE(1, 32);                     // 6 outstanding
    int cur = 0, pre = 2;
    for (int kt = 0; kt < NK; kt++) {
        if (kt < NK - 1) {
            asm volatile("s_waitcnt vmcnt(3)" ::: "memory");   // stage(kt) landed
        } else {
            asm volatile("s_waitcnt vmcnt(0)" ::: "memory");
        }
        __builtin_amdgcn_s_barrier();          // all waves' stage(kt) landed; prev reads drained
        asm volatile("" ::: "memory");
        if (kt + 2 < NK) STAGE(pre, (kt + 2) * 32);   // 2-deep prefetch, distinct buffer
        short8 af[4], bf[2];
        #pragma unroll
        for (int i = 0; i < 4; i++) af[i] = *(const short8*)(As[cur] + aoff[i]);
        #pragma unroll
        for (int j = 0; j < 2; j++) bf[j] = *(const short8*)(Bs[cur] + boff[j]);
        __builtin_amdgcn_s_setprio(1);
        #pragma unroll
        for (int i = 0; i < 4; i++)
            #pragma unroll
            for (int j = 0; j < 2; j++)
                acc[i][j] = __builtin_amdgcn_mfma_f32_16x16x32_bf16(af[i], bf[j], acc[i][j], 0, 0, 0);
        __builtin_amdgcn_s_setprio(0);
        asm volatile("s_waitcnt lgkmcnt(0)" ::: "memory");
        __builtin_amdgcn_sched_barrier(0);
        cur = (cur == 2) ? 0 : cur + 1;
        pre = (pre == 2) ? 0 : pre + 1;
    }
    #undef STAGE
    asm volatile("" ::: "memory");             // keep epilogue loads out of the loop

    // epilogue: per 16x16 tile, col = l15 (n), row = quad*4 + reg (m)
    #pragma unroll
    for (int i = 0; i < 4; i++) {
        #pragma unroll
        for (int r = 0; r < 4; r++) {
            int m = wm * 64 + i * 16 + quad * 4 + r;
            if (m >= rows) continue;
            size_t row = (size_t)(pos0 + m);
            if (MODE == 0) {
                if (col0 < 256) {
                    #pragma unroll
                    for (int j = 0; j < 2; j++) {
                        int n = col0 + wn * 32 + j * 16 + l15;
                        Ub[row * 256 + n] = (half_t)acc[i][j][r];
                    }
                } else {
                    #pragma unroll
                    for (int j = 0; j < 2; j++) {
                        int n = col0 - 256 + wn * 32 + j * 16 + l15;
                        float v = acc[i][j][r];
                        SHb[row * 512 + n] = f2bf(v * sigm(v));
                    }
                }
            } else if (MODE == 1) {
                int region = col0 >> 8;  // block-uniform
                #pragma unroll
                for (int j = 0; j < 2; j++) {
                    int n0 = (col0 & 255) + wn * 32 + j * 16 + l15;
                    size_t idx = row * 256 + (size_t)n0;
                    float v = acc[i][j][r];
                    if (region == 0) {
                        Aa[idx] = (half_t)sigm(v);
                    } else if (region == 1) {
                        Wg[idx] = (half_t)(ftanh(v) * (float)Ub[idx]);
                    } else if (region == 2) {
                        Cc[idx] = (half_t)ftanh(v);
                    } else {
                        Sk[idx] = (half_t)(dparam[e * 256 + n0] * sigm(v) * (float)Ub[idx]);
                    }
                }
            } else {
                int tok = perm[row];
                #pragma unroll
                for (int j = 0; j < 2; j++) {
                    int n = col0 + wn * 32 + j * 16 + l15;
                    out[(size_t)tok * 1024 + n] = acc[i][j][r];
                }
            }
        }
    }
}

// ---------------- K8a: chunk-local affine composition ----------------
__global__ void k_scanA(const half_t* __restrict__ Aa, const half_t* __restrict__ Wg,
                        const int* __restrict__ cStart, const int* __restrict__ cLen,
                        const int* __restrict__ meta,
                        float* __restrict__ SA, float* __restrict__ SQ) {
    int id = blockIdx.x;
    if (id >= meta[1]) return;
    int t = threadIdx.x;
    int s0 = cStart[id], L = cLen[id];
    size_t idx = (size_t)s0 * 256 + t;
    float p = 1.0f, q = 0.0f;
    for (int i = 0; i < L; i++) {
        float a = (float)Aa[idx], ww = (float)Wg[idx];
        q = a * q + ww;
        p *= a;
        idx += 256;
    }
    SA[(size_t)id * 256 + t] = p;
    SQ[(size_t)id * 256 + t] = q;
}

// ---------------- K8b: per-group serial combine -> chunk h_in ----------------
__global__ void k_scanB(const float* __restrict__ SA, const float* __restrict__ SQ,
                        const int* __restrict__ gBase, const int* __restrict__ cnt,
                        float* __restrict__ Hin) {
    int g = blockIdx.x, t = threadIdx.x;
    int base = gBase[g], nch = (cnt[g] + CHUNK - 1) / CHUNK;
    float h = 0.0f;
    for (int c = 0; c < nch; c++) {
        size_t k = (size_t)(base + c) * 256 + t;
        Hin[k] = h;
        h = SA[k] * h + SQ[k];
    }
}

// ---------------- K8c: re-scan with h_in, emit y (bf16) ----------------
__global__ void k_scanC(const half_t* __restrict__ Aa, const half_t* __restrict__ Wg,
                        const half_t* __restrict__ Cc, const half_t* __restrict__ Sk,
                        const int* __restrict__ cStart, const int* __restrict__ cLen,
                        const int* __restrict__ meta, const float* __restrict__ Hin,
                        unsigned short* __restrict__ Yb) {
    int id = blockIdx.x;
    if (id >= meta[1]) return;
    int t = threadIdx.x;
    int s0 = cStart[id], L = cLen[id];
    float h = Hin[(size_t)id * 256 + t];
    size_t idx = (size_t)s0 * 256 + t;
    for (int i = 0; i < L; i++) {
        float a = (float)Aa[idx], ww = (float)Wg[idx];
        float c = (float)Cc[idx], sk = (float)Sk[idx];
        h = a * h + ww;
        Yb[idx] = f2bf(c * h + sk);
        idx += 256;
    }
}

extern "C" void kernel_launch(void* const* d_in, const int* in_sizes, int n_in,
                              void* d_out, int out_size, void* d_ws, size_t ws_size,
                              hipStream_t stream) {
    const float* xin   = (const float*)d_in[0];
    const int*   tok   = (const int*)d_in[1];
    const float* Win   = (const float*)d_in[2];
    const float* Wsin  = (const float*)d_in[3];
    const float* Wsout = (const float*)d_in[4];
    const float* Wout  = (const float*)d_in[5];
    const float* dpar  = (const float*)d_in[6];
    float* out = (float*)d_out;

    size_t off = 0;
    char* base = (char*)d_ws;
    auto alloc = [&](size_t bytes) -> void* {
        void* p = base + off;
        off += (bytes + 255) & ~(size_t)255;
        return p;
    };
    half_t*         Ub  = (half_t*)alloc((size_t)RPAD * NN * 2);
    unsigned short* SHb = (unsigned short*)alloc((size_t)RPAD * HH * 2);
    unsigned short* Xs  = (unsigned short*)alloc((size_t)RPAD * DD * 2);
    unsigned short* Yb  = (unsigned short*)alloc((size_t)RPAD * NN * 2);
    half_t* Aa = (half_t*)alloc((size_t)TOKS * NN * 2);
    half_t* Wg = (half_t*)alloc((size_t)TOKS * NN * 2);
    half_t* Cc = (half_t*)alloc((size_t)TOKS * NN * 2);
    half_t* Sk = (half_t*)alloc((size_t)TOKS * NN * 2);
    unsigned short* W12 = (unsigned short*)alloc((size_t)8 * 768 * 1024 * 2);
    unsigned short* Wso = (unsigned short*)alloc((size_t)8 * 1024 * 512 * 2);
    unsigned short* Wo  = (unsigned short*)alloc((size_t)8 * 1024 * 256 * 2);
    float* SA  = (float*)alloc((size_t)MAXCHUNKS * 256 * 4);
    float* SQ  = (float*)alloc((size_t)MAXCHUNKS * 256 * 4);
    float* Hin = (float*)alloc((size_t)MAXCHUNKS * 256 * 4);
    int* perm   = (int*)alloc(TOKS * 4);
    int* cnt    = (int*)alloc(64 * 4);
    int* grpoff = (int*)alloc(64 * 4);
    int* tileE  = (int*)alloc(MAXTILES * 4);
    int* tileS  = (int*)alloc(MAXTILES * 4);
    int* tileR  = (int*)alloc(MAXTILES * 4);
    int* cGrp   = (int*)alloc(MAXCHUNKS * 4);
    int* cStart = (int*)alloc(MAXCHUNKS * 4);
    int* cLen   = (int*)alloc(MAXCHUNKS * 4);
    int* gBase  = (int*)alloc(64 * 4);
    int* meta   = (int*)alloc(16 * 4);

    k_route<<<8, 256, 0, stream>>>(tok, cnt);
    k_offsets<<<1, 256, 0, stream>>>(cnt, grpoff, tileE, tileS, tileR,
                                     cGrp, cStart, cLen, gBase, meta);
    k_scatter<<<8, 256, 0, stream>>>(tok, grpoff, perm);
    k_prep<<<CVTBLKS + RPAD, 256, 0, stream>>>(Win, Wsin, Wsout, Wout, W12, Wso, Wo,
                                               xin, perm, Xs, SHb, Yb);

    k_mfma<0, 1024><<<dim3(MAXTILES, 12), 256, 0, stream>>>(Xs, W12, perm, dpar,
        Ub, SHb, Aa, Wg, Cc, Sk, out, tileE, tileS, tileR, meta);
    k_mfma<1, 512><<<dim3(MAXTILES, 16), 256, 0, stream>>>(SHb, Wso, perm, dpar,
        Ub, SHb, Aa, Wg, Cc, Sk, out, tileE, tileS, tileR, meta);

    k_scanA<<<MAXCHUNKS, 256, 0, stream>>>(Aa, Wg, cStart, cLen, meta, SA, SQ);
    k_scanB<<<64, 256, 0, stream>>>(SA, SQ, gBase, cnt, Hin);
    k_scanC<<<MAXCHUNKS, 256, 0, stream>>>(Aa, Wg, Cc, Sk, cStart, cLen, meta, Hin, Yb);

    k_mfma<2, 256><<<dim3(MAXTILES, 16), 256, 0, stream>>>(Yb, Wo, perm, dpar,
        Ub, SHb, Aa, Wg, Cc, Sk, out, tileE, tileS, tileR, meta);
}